// Round 1
// baseline (651.692 us; speedup 1.0000x reference)
//
#include <hip/hip_runtime.h>
#include <math.h>

#define SH_C0f 0.28209479177387814f
#define SH_C1f 0.4886025119029199f
#define EPS2D 0.3f
#define NEAR_PLANE 0.01f
#define FAR_PLANE 1e10f
#define ALPHA_MIN (1.0f/255.0f)
#define ALPHA_MAX 0.999f
#define T_EPS 1e-4f

// ---------------- kernel 1: general 4x4 inverse (1 thread) ----------------
__global__ void invert4_kernel(const float* __restrict__ m_in, float* __restrict__ out16) {
    float m[16];
    #pragma unroll
    for (int i = 0; i < 16; i++) m[i] = m_in[i];
    float inv[16];
    inv[0]  =  m[5]*m[10]*m[15] - m[5]*m[11]*m[14] - m[9]*m[6]*m[15] + m[9]*m[7]*m[14] + m[13]*m[6]*m[11] - m[13]*m[7]*m[10];
    inv[4]  = -m[4]*m[10]*m[15] + m[4]*m[11]*m[14] + m[8]*m[6]*m[15] - m[8]*m[7]*m[14] - m[12]*m[6]*m[11] + m[12]*m[7]*m[10];
    inv[8]  =  m[4]*m[9]*m[15]  - m[4]*m[11]*m[13] - m[8]*m[5]*m[15] + m[8]*m[7]*m[13] + m[12]*m[5]*m[11] - m[12]*m[7]*m[9];
    inv[12] = -m[4]*m[9]*m[14]  + m[4]*m[10]*m[13] + m[8]*m[5]*m[14] - m[8]*m[6]*m[13] - m[12]*m[5]*m[10] + m[12]*m[6]*m[9];
    inv[1]  = -m[1]*m[10]*m[15] + m[1]*m[11]*m[14] + m[9]*m[2]*m[15] - m[9]*m[3]*m[14] - m[13]*m[2]*m[11] + m[13]*m[3]*m[10];
    inv[5]  =  m[0]*m[10]*m[15] - m[0]*m[11]*m[14] - m[8]*m[2]*m[15] + m[8]*m[3]*m[14] + m[12]*m[2]*m[11] - m[12]*m[3]*m[10];
    inv[9]  = -m[0]*m[9]*m[15]  + m[0]*m[11]*m[13] + m[8]*m[1]*m[15] - m[8]*m[3]*m[13] - m[12]*m[1]*m[11] + m[12]*m[3]*m[9];
    inv[13] =  m[0]*m[9]*m[14]  - m[0]*m[10]*m[13] - m[8]*m[1]*m[14] + m[8]*m[2]*m[13] + m[12]*m[1]*m[10] - m[12]*m[2]*m[9];
    inv[2]  =  m[1]*m[6]*m[15]  - m[1]*m[7]*m[14]  - m[5]*m[2]*m[15] + m[5]*m[3]*m[14] + m[13]*m[2]*m[7]  - m[13]*m[3]*m[6];
    inv[6]  = -m[0]*m[6]*m[15]  + m[0]*m[7]*m[14]  + m[4]*m[2]*m[15] - m[4]*m[3]*m[14] - m[12]*m[2]*m[7]  + m[12]*m[3]*m[6];
    inv[10] =  m[0]*m[5]*m[15]  - m[0]*m[7]*m[13]  - m[4]*m[1]*m[15] + m[4]*m[3]*m[13] + m[12]*m[1]*m[7]  - m[12]*m[3]*m[5];
    inv[14] = -m[0]*m[5]*m[14]  + m[0]*m[6]*m[13]  + m[4]*m[1]*m[14] - m[4]*m[2]*m[13] - m[12]*m[1]*m[6]  + m[12]*m[2]*m[5];
    inv[3]  = -m[1]*m[6]*m[11]  + m[1]*m[7]*m[10]  + m[5]*m[2]*m[11] - m[5]*m[3]*m[10] - m[9]*m[2]*m[7]   + m[9]*m[3]*m[6];
    inv[7]  =  m[0]*m[6]*m[11]  - m[0]*m[7]*m[10]  - m[4]*m[2]*m[11] + m[4]*m[3]*m[10] + m[8]*m[2]*m[7]   - m[8]*m[3]*m[6];
    inv[11] = -m[0]*m[5]*m[11]  + m[0]*m[7]*m[9]   + m[4]*m[1]*m[11] - m[4]*m[3]*m[9]  - m[8]*m[1]*m[7]   + m[8]*m[3]*m[5];
    inv[15] =  m[0]*m[5]*m[10]  - m[0]*m[6]*m[9]   - m[4]*m[1]*m[10] + m[4]*m[2]*m[9]  + m[8]*m[1]*m[6]   - m[8]*m[2]*m[5];
    float det = m[0]*inv[0] + m[1]*inv[4] + m[2]*inv[8] + m[3]*inv[12];
    float r = 1.0f / det;
    #pragma unroll
    for (int i = 0; i < 16; i++) out16[i] = inv[i] * r;
}

// ---------------- kernel 2: per-gaussian preprocess ----------------
__global__ void preprocess_kernel(
    const float* __restrict__ means, const float* __restrict__ opac_in,
    const float* __restrict__ scales, const float* __restrict__ quats,
    const float* __restrict__ sh0, const float* __restrict__ shN,
    const float* __restrict__ c2w, const float* __restrict__ Ks,
    const int* __restrict__ wptr, const int* __restrict__ hptr,
    const float* __restrict__ vm,
    float* __restrict__ tz_u, float* __restrict__ mx_u, float* __restrict__ my_u,
    float* __restrict__ A_u, float* __restrict__ B_u, float* __restrict__ C_u,
    float* __restrict__ op_u, float* __restrict__ r_u, float* __restrict__ g_u,
    float* __restrict__ b_u, int N)
{
    int i = blockIdx.x * blockDim.x + threadIdx.x;
    if (i >= N) return;

    const float fx = Ks[0], cx = Ks[2], fy = Ks[4], cy = Ks[5];
    const float width = (float)wptr[0], height = (float)hptr[0];

    const float W00 = vm[0],  W01 = vm[1],  W02 = vm[2],  t0 = vm[3];
    const float W10 = vm[4],  W11 = vm[5],  W12 = vm[6],  t1 = vm[7];
    const float W20 = vm[8],  W21 = vm[9],  W22 = vm[10], t2 = vm[11];

    const float mxx = means[i*3+0], myy = means[i*3+1], mzz = means[i*3+2];

    // view direction from camera position (camtoworlds[0,:3,3])
    const float cpx = c2w[3], cpy = c2w[7], cpz = c2w[11];
    float dx = mxx - cpx, dy = myy - cpy, dz = mzz - cpz;
    float dn = sqrtf(dx*dx + dy*dy + dz*dz);
    dx /= dn; dy /= dn; dz /= dn;

    // SH degree-1 color
    float col[3];
    #pragma unroll
    for (int c = 0; c < 3; c++) {
        float v = SH_C0f * sh0[i*3+c]
                + SH_C1f * (-dy * shN[i*9 + 0*3 + c] + dz * shN[i*9 + 1*3 + c] - dx * shN[i*9 + 2*3 + c])
                + 0.5f;
        col[c] = fmaxf(v, 0.0f);
    }

    // sigmoid opacity
    const float op = 1.0f / (1.0f + expf(-opac_in[i]));

    // quat -> R (normalized)
    float qw = quats[i*4+0], qx = quats[i*4+1], qy = quats[i*4+2], qz = quats[i*4+3];
    float qn = sqrtf(qw*qw + qx*qx + qy*qy + qz*qz);
    qw /= qn; qx /= qn; qy /= qn; qz /= qn;
    const float R00 = 1.f - 2.f*(qy*qy + qz*qz), R01 = 2.f*(qx*qy - qw*qz), R02 = 2.f*(qx*qz + qw*qy);
    const float R10 = 2.f*(qx*qy + qw*qz), R11 = 1.f - 2.f*(qx*qx + qz*qz), R12 = 2.f*(qy*qz - qw*qx);
    const float R20 = 2.f*(qx*qz - qw*qy), R21 = 2.f*(qy*qz + qw*qx), R22 = 1.f - 2.f*(qx*qx + qy*qy);

    const float sx = scales[i*3+0], sy = scales[i*3+1], sz = scales[i*3+2];
    const float M00 = R00*sx, M01 = R01*sy, M02 = R02*sz;
    const float M10 = R10*sx, M11 = R11*sy, M12 = R12*sz;
    const float M20 = R20*sx, M21 = R21*sy, M22 = R22*sz;

    // cov3d = M M^T (symmetric)
    const float S00 = M00*M00 + M01*M01 + M02*M02;
    const float S01 = M00*M10 + M01*M11 + M02*M12;
    const float S02 = M00*M20 + M01*M21 + M02*M22;
    const float S11 = M10*M10 + M11*M11 + M12*M12;
    const float S12 = M10*M20 + M11*M21 + M12*M22;
    const float S22 = M20*M20 + M21*M21 + M22*M22;

    // camera-space mean
    const float tcx = W00*mxx + W01*myy + W02*mzz + t0;
    const float tcy = W10*mxx + W11*myy + W12*mzz + t1;
    const float tcz = W20*mxx + W21*myy + W22*mzz + t2;
    const float rz = 1.0f / tcz;

    const float limx = 1.3f * (0.5f * width / fx);
    const float limy = 1.3f * (0.5f * height / fy);
    const float txz = fminf(fmaxf(tcx * rz, -limx), limx);
    const float tyz = fminf(fmaxf(tcy * rz, -limy), limy);

    // cov_cam = W3 S W3^T
    const float V00 = W00*S00 + W01*S01 + W02*S02;
    const float V01 = W00*S01 + W01*S11 + W02*S12;
    const float V02 = W00*S02 + W01*S12 + W02*S22;
    const float V10 = W10*S00 + W11*S01 + W12*S02;
    const float V11 = W10*S01 + W11*S11 + W12*S12;
    const float V12 = W10*S02 + W11*S12 + W12*S22;
    const float V20 = W20*S00 + W21*S01 + W22*S02;
    const float V21 = W20*S01 + W21*S11 + W22*S12;
    const float V22 = W20*S02 + W21*S12 + W22*S22;
    const float CC00 = V00*W00 + V01*W01 + V02*W02;
    const float CC01 = V00*W10 + V01*W11 + V02*W12;
    const float CC02 = V00*W20 + V01*W21 + V02*W22;
    const float CC11 = V10*W10 + V11*W11 + V12*W12;
    const float CC12 = V10*W20 + V11*W21 + V12*W22;
    const float CC22 = V20*W20 + V21*W21 + V22*W22;

    // J (2x3)
    const float j00 = fx * rz,  j02 = -fx * txz * rz;
    const float j11 = fy * rz,  j12 = -fy * tyz * rz;

    // cov2d = J CC J^T
    const float u0 = j00*CC00 + j02*CC02;
    const float u1 = j00*CC01 + j02*CC12;
    const float u2 = j00*CC02 + j02*CC22;
    const float v1 = j11*CC11 + j12*CC12;
    const float v2 = j11*CC12 + j12*CC22;
    const float c2d00 = u0*j00 + u2*j02;
    const float c2d01 = u1*j11 + u2*j12;
    const float c2d11 = v1*j11 + v2*j12;

    const float a  = c2d00 + EPS2D;
    const float bb = c2d01;
    const float cc = c2d11 + EPS2D;
    const float det = a*cc - bb*bb;
    const float det_safe = (det > 0.0f) ? det : 1.0f;
    const float invd = 1.0f / det_safe;

    const bool valid = (tcz > NEAR_PLANE) && (tcz < FAR_PLANE) && (det > 0.0f);

    tz_u[i] = tcz;
    mx_u[i] = fx * tcx * rz + cx;
    my_u[i] = fy * tcy * rz + cy;
    A_u[i]  = cc * invd;
    B_u[i]  = -bb * invd;
    C_u[i]  = a * invd;
    op_u[i] = valid ? op : -1.0f;   // invalid encoded as negative opacity
    r_u[i]  = col[0];
    g_u[i]  = col[1];
    b_u[i]  = col[2];
}

// ---------------- kernel 3: stable O(N^2) rank sort + scatter ----------------
__global__ void sort_scatter_kernel(
    const float* __restrict__ tz_u, const float* __restrict__ mx_u, const float* __restrict__ my_u,
    const float* __restrict__ A_u, const float* __restrict__ B_u, const float* __restrict__ C_u,
    const float* __restrict__ op_u, const float* __restrict__ r_u, const float* __restrict__ g_u,
    const float* __restrict__ b_u,
    float* __restrict__ tz_s, float* __restrict__ mx_s, float* __restrict__ my_s,
    float* __restrict__ A_s, float* __restrict__ B_s, float* __restrict__ C_s,
    float* __restrict__ op_s, float* __restrict__ r_s, float* __restrict__ g_s,
    float* __restrict__ b_s, int N)
{
    extern __shared__ float skey[];
    for (int j = threadIdx.x; j < N; j += blockDim.x) skey[j] = tz_u[j];
    __syncthreads();

    int i = blockIdx.x * blockDim.x + threadIdx.x;
    if (i >= N) return;
    const float k = skey[i];
    int rank = 0;
    for (int j = 0; j < N; j++) {
        const float kj = skey[j];
        rank += (kj < k) || (kj == k && j < i);
    }
    tz_s[rank] = k;
    mx_s[rank] = mx_u[i];
    my_s[rank] = my_u[i];
    A_s[rank]  = A_u[i];
    B_s[rank]  = B_u[i];
    C_s[rank]  = C_u[i];
    op_s[rank] = op_u[i];
    r_s[rank]  = r_u[i];
    g_s[rank]  = g_u[i];
    b_s[rank]  = b_u[i];
}

// ---------------- kernel 4: rasterize ----------------
#define CHUNK 256
__global__ __launch_bounds__(256) void raster_kernel(
    const float* __restrict__ tz_s, const float* __restrict__ mx_s, const float* __restrict__ my_s,
    const float* __restrict__ A_s, const float* __restrict__ B_s, const float* __restrict__ C_s,
    const float* __restrict__ op_s, const float* __restrict__ r_s, const float* __restrict__ g_s,
    const float* __restrict__ b_s,
    float* __restrict__ out, int N, int P, const int* __restrict__ wptr)
{
    __shared__ float s_mx[CHUNK], s_my[CHUNK], s_A[CHUNK], s_B[CHUNK], s_C[CHUNK];
    __shared__ float s_op[CHUNK], s_r[CHUNK], s_g[CHUNK], s_b[CHUNK], s_tz[CHUNK];

    const int pix = blockIdx.x * blockDim.x + threadIdx.x;
    const int width = wptr[0];
    const bool active = pix < P;
    float px = 0.f, py = 0.f;
    if (active) {
        px = (float)(pix % width) + 0.5f;
        py = (float)(pix / width) + 0.5f;
    }

    float T = 1.0f;
    float accr = 0.f, accg = 0.f, accb = 0.f, accd = 0.f, acca = 0.f;
    bool done = !active;

    for (int base = 0; base < N; base += CHUNK) {
        const int cnt = min(CHUNK, N - base);
        for (int j = threadIdx.x; j < cnt; j += blockDim.x) {
            s_mx[j] = mx_s[base + j];
            s_my[j] = my_s[base + j];
            s_A[j]  = A_s[base + j];
            s_B[j]  = B_s[base + j];
            s_C[j]  = C_s[base + j];
            s_op[j] = op_s[base + j];
            s_r[j]  = r_s[base + j];
            s_g[j]  = g_s[base + j];
            s_b[j]  = b_s[base + j];
            s_tz[j] = tz_s[base + j];
        }
        __syncthreads();

        if (!done) {
            for (int j = 0; j < cnt; j++) {
                const float op = s_op[j];
                if (op <= 0.0f) continue;          // invalid gaussian
                const float ddx = px - s_mx[j];
                const float ddy = py - s_my[j];
                const float sigma = 0.5f * (s_A[j]*ddx*ddx + s_C[j]*ddy*ddy) + s_B[j]*ddx*ddy;
                if (sigma < 0.0f) continue;
                float alpha = op * expf(-sigma);
                if (alpha < ALPHA_MIN) continue;
                alpha = fminf(alpha, ALPHA_MAX);
                const float w = alpha * T;
                accr += w * s_r[j];
                accg += w * s_g[j];
                accb += w * s_b[j];
                accd += w * s_tz[j];
                acca += w;
                T *= (1.0f - alpha);
                if (T <= T_EPS) { done = true; break; }
            }
        }
        if (__syncthreads_and((int)done)) break;
    }

    if (active) {
        out[pix*4 + 0] = accr;
        out[pix*4 + 1] = accg;
        out[pix*4 + 2] = accb;
        out[pix*4 + 3] = accd / fmaxf(acca, 1e-10f);
        out[(size_t)P*4 + pix] = acca;
    }
}

// ---------------- host-side launch ----------------
extern "C" void kernel_launch(void* const* d_in, const int* in_sizes, int n_in,
                              void* d_out, int out_size, void* d_ws, size_t ws_size,
                              hipStream_t stream) {
    const float* means   = (const float*)d_in[0];
    const float* opac    = (const float*)d_in[1];
    const float* scales  = (const float*)d_in[2];
    const float* quats   = (const float*)d_in[3];
    const float* sh0     = (const float*)d_in[4];
    const float* shN     = (const float*)d_in[5];
    const float* c2w     = (const float*)d_in[6];
    const float* Ks      = (const float*)d_in[7];
    const int*   wptr    = (const int*)d_in[8];
    const int*   hptr    = (const int*)d_in[9];

    const int N = in_sizes[0] / 3;
    const int P = out_size / 5;

    float* ws = (float*)d_ws;
    float* vm = ws;                 // 16 floats
    float* base = ws + 16;
    float* tz_u = base + 0*N;  float* mx_u = base + 1*N;  float* my_u = base + 2*N;
    float* A_u  = base + 3*N;  float* B_u  = base + 4*N;  float* C_u  = base + 5*N;
    float* op_u = base + 6*N;  float* r_u  = base + 7*N;  float* g_u  = base + 8*N;
    float* b_u  = base + 9*N;
    float* tz_s = base + 10*N; float* mx_s = base + 11*N; float* my_s = base + 12*N;
    float* A_s  = base + 13*N; float* B_s  = base + 14*N; float* C_s  = base + 15*N;
    float* op_s = base + 16*N; float* r_s  = base + 17*N; float* g_s  = base + 18*N;
    float* b_s  = base + 19*N;

    hipLaunchKernelGGL(invert4_kernel, dim3(1), dim3(1), 0, stream, c2w, vm);

    const int gb = (N + 255) / 256;
    hipLaunchKernelGGL(preprocess_kernel, dim3(gb), dim3(256), 0, stream,
                       means, opac, scales, quats, sh0, shN, c2w, Ks, wptr, hptr, vm,
                       tz_u, mx_u, my_u, A_u, B_u, C_u, op_u, r_u, g_u, b_u, N);

    hipLaunchKernelGGL(sort_scatter_kernel, dim3(gb), dim3(256), N * sizeof(float), stream,
                       tz_u, mx_u, my_u, A_u, B_u, C_u, op_u, r_u, g_u, b_u,
                       tz_s, mx_s, my_s, A_s, B_s, C_s, op_s, r_s, g_s, b_s, N);

    const int pb = (P + 255) / 256;
    hipLaunchKernelGGL(raster_kernel, dim3(pb), dim3(256), 0, stream,
                       tz_s, mx_s, my_s, A_s, B_s, C_s, op_s, r_s, g_s, b_s,
                       (float*)d_out, N, P, wptr);
}

// Round 2
// 111.074 us; speedup vs baseline: 5.8672x; 5.8672x over previous
//
#include <hip/hip_runtime.h>
#include <math.h>

#define SH_C0f 0.28209479177387814f
#define SH_C1f 0.4886025119029199f
#define EPS2D 0.3f
#define NEAR_PLANE 0.01f
#define FAR_PLANE 1e10f
#define ALPHA_MIN (1.0f/255.0f)
#define ALPHA_MAX 0.999f
#define T_EPS 1e-4f
#define TS 8   // tile size (8x8 pixels, one wave per tile)

// ---------------- kernel 1: per-gaussian preprocess (inline 4x4 inverse) ---
__global__ void preprocess_kernel(
    const float* __restrict__ means, const float* __restrict__ opac_in,
    const float* __restrict__ scales, const float* __restrict__ quats,
    const float* __restrict__ sh0, const float* __restrict__ shN,
    const float* __restrict__ c2w, const float* __restrict__ Ks,
    const int* __restrict__ wptr, const int* __restrict__ hptr,
    float4* __restrict__ attrs, float* __restrict__ tz_arr, int N)
{
    int i = blockIdx.x * blockDim.x + threadIdx.x;
    if (i >= N) return;

    // ---- inline general 4x4 inverse of camtoworlds (rows 0..2 needed) ----
    float m[16];
    #pragma unroll
    for (int k = 0; k < 16; k++) m[k] = c2w[k];
    float inv[12];
    inv[0]  =  m[5]*m[10]*m[15] - m[5]*m[11]*m[14] - m[9]*m[6]*m[15] + m[9]*m[7]*m[14] + m[13]*m[6]*m[11] - m[13]*m[7]*m[10];
    inv[4]  = -m[4]*m[10]*m[15] + m[4]*m[11]*m[14] + m[8]*m[6]*m[15] - m[8]*m[7]*m[14] - m[12]*m[6]*m[11] + m[12]*m[7]*m[10];
    inv[8]  =  m[4]*m[9]*m[15]  - m[4]*m[11]*m[13] - m[8]*m[5]*m[15] + m[8]*m[7]*m[13] + m[12]*m[5]*m[11] - m[12]*m[7]*m[9];
    inv[1]  = -m[1]*m[10]*m[15] + m[1]*m[11]*m[14] + m[9]*m[2]*m[15] - m[9]*m[3]*m[14] - m[13]*m[2]*m[11] + m[13]*m[3]*m[10];
    inv[5]  =  m[0]*m[10]*m[15] - m[0]*m[11]*m[14] - m[8]*m[2]*m[15] + m[8]*m[3]*m[14] + m[12]*m[2]*m[11] - m[12]*m[3]*m[10];
    inv[9]  = -m[0]*m[9]*m[15]  + m[0]*m[11]*m[13] + m[8]*m[1]*m[15] - m[8]*m[3]*m[13] - m[12]*m[1]*m[11] + m[12]*m[3]*m[9];
    inv[2]  =  m[1]*m[6]*m[15]  - m[1]*m[7]*m[14]  - m[5]*m[2]*m[15] + m[5]*m[3]*m[14] + m[13]*m[2]*m[7]  - m[13]*m[3]*m[6];
    inv[6]  = -m[0]*m[6]*m[15]  + m[0]*m[7]*m[14]  + m[4]*m[2]*m[15] - m[4]*m[3]*m[14] - m[12]*m[2]*m[7]  + m[12]*m[3]*m[6];
    inv[10] =  m[0]*m[5]*m[15]  - m[0]*m[7]*m[13]  - m[4]*m[1]*m[15] + m[4]*m[3]*m[13] + m[12]*m[1]*m[7]  - m[12]*m[3]*m[5];
    inv[3]  = -m[1]*m[6]*m[11]  + m[1]*m[7]*m[10]  + m[5]*m[2]*m[11] - m[5]*m[3]*m[10] - m[9]*m[2]*m[7]   + m[9]*m[3]*m[6];
    inv[7]  =  m[0]*m[6]*m[11]  - m[0]*m[7]*m[10]  - m[4]*m[2]*m[11] + m[4]*m[3]*m[10] + m[8]*m[2]*m[7]   - m[8]*m[3]*m[6];
    inv[11] = -m[0]*m[5]*m[11]  + m[0]*m[7]*m[9]   + m[4]*m[1]*m[11] - m[4]*m[3]*m[9]  - m[8]*m[1]*m[7]   + m[8]*m[3]*m[5];
    {
        // det via full first column cofactors (needs inv[12] term)
        float inv12 = -m[4]*m[9]*m[14] + m[4]*m[10]*m[13] + m[8]*m[5]*m[14] - m[8]*m[6]*m[13] - m[12]*m[5]*m[10] + m[12]*m[6]*m[9];
        float det = m[0]*inv[0] + m[1]*inv[4] + m[2]*inv[8] + m[3]*inv12;
        float r = 1.0f / det;
        #pragma unroll
        for (int k = 0; k < 12; k++) inv[k] *= r;
    }
    const float W00 = inv[0], W01 = inv[1], W02 = inv[2],  t0 = inv[3];
    const float W10 = inv[4], W11 = inv[5], W12 = inv[6],  t1 = inv[7];
    const float W20 = inv[8], W21 = inv[9], W22 = inv[10], t2 = inv[11];

    const float fx = Ks[0], cx = Ks[2], fy = Ks[4], cy = Ks[5];
    const float width = (float)wptr[0], height = (float)hptr[0];

    const float mxx = means[i*3+0], myy = means[i*3+1], mzz = means[i*3+2];

    // view direction from camera position (camtoworlds[0,:3,3])
    const float cpx = m[3], cpy = m[7], cpz = m[11];
    float dx = mxx - cpx, dy = myy - cpy, dz = mzz - cpz;
    float dn = sqrtf(dx*dx + dy*dy + dz*dz);
    dx /= dn; dy /= dn; dz /= dn;

    // SH degree-1 color
    float col[3];
    #pragma unroll
    for (int c = 0; c < 3; c++) {
        float v = SH_C0f * sh0[i*3+c]
                + SH_C1f * (-dy * shN[i*9 + 0*3 + c] + dz * shN[i*9 + 1*3 + c] - dx * shN[i*9 + 2*3 + c])
                + 0.5f;
        col[c] = fmaxf(v, 0.0f);
    }

    // sigmoid opacity
    const float op = 1.0f / (1.0f + expf(-opac_in[i]));

    // quat -> R (normalized)
    float qw = quats[i*4+0], qx = quats[i*4+1], qy = quats[i*4+2], qz = quats[i*4+3];
    float qn = sqrtf(qw*qw + qx*qx + qy*qy + qz*qz);
    qw /= qn; qx /= qn; qy /= qn; qz /= qn;
    const float R00 = 1.f - 2.f*(qy*qy + qz*qz), R01 = 2.f*(qx*qy - qw*qz), R02 = 2.f*(qx*qz + qw*qy);
    const float R10 = 2.f*(qx*qy + qw*qz), R11 = 1.f - 2.f*(qx*qx + qz*qz), R12 = 2.f*(qy*qz - qw*qx);
    const float R20 = 2.f*(qx*qz - qw*qy), R21 = 2.f*(qy*qz + qw*qx), R22 = 1.f - 2.f*(qx*qx + qy*qy);

    const float sx = scales[i*3+0], sy = scales[i*3+1], sz = scales[i*3+2];
    const float M00 = R00*sx, M01 = R01*sy, M02 = R02*sz;
    const float M10 = R10*sx, M11 = R11*sy, M12 = R12*sz;
    const float M20 = R20*sx, M21 = R21*sy, M22 = R22*sz;

    // cov3d = M M^T (symmetric)
    const float S00 = M00*M00 + M01*M01 + M02*M02;
    const float S01 = M00*M10 + M01*M11 + M02*M12;
    const float S02 = M00*M20 + M01*M21 + M02*M22;
    const float S11 = M10*M10 + M11*M11 + M12*M12;
    const float S12 = M10*M20 + M11*M21 + M12*M22;
    const float S22 = M20*M20 + M21*M21 + M22*M22;

    // camera-space mean
    const float tcx = W00*mxx + W01*myy + W02*mzz + t0;
    const float tcy = W10*mxx + W11*myy + W12*mzz + t1;
    const float tcz = W20*mxx + W21*myy + W22*mzz + t2;
    const float rz = 1.0f / tcz;

    const float limx = 1.3f * (0.5f * width / fx);
    const float limy = 1.3f * (0.5f * height / fy);
    const float txz = fminf(fmaxf(tcx * rz, -limx), limx);
    const float tyz = fminf(fmaxf(tcy * rz, -limy), limy);

    // cov_cam = W3 S W3^T
    const float V00 = W00*S00 + W01*S01 + W02*S02;
    const float V01 = W00*S01 + W01*S11 + W02*S12;
    const float V02 = W00*S02 + W01*S12 + W02*S22;
    const float V10 = W10*S00 + W11*S01 + W12*S02;
    const float V11 = W10*S01 + W11*S11 + W12*S12;
    const float V12 = W10*S02 + W11*S12 + W12*S22;
    const float V20 = W20*S00 + W21*S01 + W22*S02;
    const float V21 = W20*S01 + W21*S11 + W22*S12;
    const float V22 = W20*S02 + W21*S12 + W22*S22;
    const float CC00 = V00*W00 + V01*W01 + V02*W02;
    const float CC01 = V00*W10 + V01*W11 + V02*W12;
    const float CC02 = V00*W20 + V01*W21 + V02*W22;
    const float CC11 = V10*W10 + V11*W11 + V12*W12;
    const float CC12 = V10*W20 + V11*W21 + V12*W22;
    const float CC22 = V20*W20 + V21*W21 + V22*W22;

    // J (2x3)
    const float j00 = fx * rz,  j02 = -fx * txz * rz;
    const float j11 = fy * rz,  j12 = -fy * tyz * rz;

    // cov2d = J CC J^T
    const float u0 = j00*CC00 + j02*CC02;
    const float u1 = j00*CC01 + j02*CC12;
    const float u2 = j00*CC02 + j02*CC22;
    const float v1 = j11*CC11 + j12*CC12;
    const float v2 = j11*CC12 + j12*CC22;
    const float c2d00 = u0*j00 + u2*j02;
    const float c2d01 = u1*j11 + u2*j12;
    const float c2d11 = v1*j11 + v2*j12;

    const float a  = c2d00 + EPS2D;
    const float bb = c2d01;
    const float cc = c2d11 + EPS2D;
    const float det = a*cc - bb*bb;
    const float det_safe = (det > 0.0f) ? det : 1.0f;
    const float invd = 1.0f / det_safe;

    const bool valid = (tcz > NEAR_PLANE) && (tcz < FAR_PLANE) && (det > 0.0f);

    // conservative cull radius: alpha >= 1/255 needs sigma <= ln(255*op);
    // sigma = 0.5 d^T Sigma^-1 d >= 0.5 |d|^2 / lambda_max(Sigma)
    float rad = 0.0f;
    if (valid && op >= ALPHA_MIN) {
        const float lmax = 0.5f*(a + cc) + sqrtf(fmaxf(0.f, 0.25f*(a - cc)*(a - cc) + bb*bb));
        const float sig_cut = logf(255.0f * op);
        rad = sqrtf(fmaxf(sig_cut, 0.0f) * 2.0f * lmax) * 1.001f + 0.5f;
    }

    const float mx2d = fx * tcx * rz + cx;
    const float my2d = fy * tcy * rz + cy;

    attrs[i*3+0] = make_float4(mx2d, my2d, cc * invd, -bb * invd);   // mx, my, A, B
    attrs[i*3+1] = make_float4(a * invd, op, tcz, rad);              // C, op, tz, rad
    attrs[i*3+2] = make_float4(col[0], col[1], col[2], 0.0f);       // r, g, b
    tz_arr[i] = tcz;
}

// ---------------- kernel 2: stable O(N^2) rank sort -> permutation ---------
__global__ void sort_kernel(const float* __restrict__ tz_u, int* __restrict__ perm, int N)
{
    extern __shared__ float skey[];
    for (int j = threadIdx.x; j < N; j += blockDim.x) skey[j] = tz_u[j];
    __syncthreads();

    int i = blockIdx.x * blockDim.x + threadIdx.x;
    if (i >= N) return;
    const float k = skey[i];
    int rank = 0;
    for (int j = 0; j < N; j++) {
        const float kj = skey[j];
        rank += (kj < k) || (kj == k && j < i);
    }
    perm[rank] = i;
}

// ---------------- kernel 3: tiled rasterize (1 wave per 8x8 tile) ---------
__global__ __launch_bounds__(64) void raster_kernel(
    const float4* __restrict__ attrs, const int* __restrict__ perm,
    float* __restrict__ out, int N, int P, const int* __restrict__ wptr)
{
    extern __shared__ int s_list[];           // N ints (dynamic)
    __shared__ float4 s_g0[64], s_g1[64], s_g2[64];

    const int width  = wptr[0];
    const int height = P / width;
    const int tilesX = (width  + TS - 1) / TS;
    const int tilesY = (height + TS - 1) / TS;
    const int nTiles = tilesX * tilesY;
    const int lane = threadIdx.x;

    for (int tile = blockIdx.x; tile < nTiles; tile += gridDim.x) {
        __syncthreads();   // protect s_list reuse across grid-stride iterations

        const int tx = tile % tilesX, ty = tile / tilesX;
        const float x0 = (float)(tx*TS) + 0.5f;
        const float x1 = (float)(min(tx*TS + TS - 1, width  - 1)) + 0.5f;
        const float y0 = (float)(ty*TS) + 0.5f;
        const float y1 = (float)(min(ty*TS + TS - 1, height - 1)) + 0.5f;

        // ---- build depth-ordered intersection list (wave ballot compaction)
        int count = 0;
        for (int base = 0; base < N; base += 64) {
            const int j = base + lane;
            bool pred = false;
            int idx = 0;
            if (j < N) {
                idx = perm[j];
                const float4 g0 = attrs[idx*3+0];
                const float4 g1 = attrs[idx*3+1];
                const float rad = g1.w;
                pred = (rad > 0.0f) &&
                       (g0.x + rad >= x0) && (g0.x - rad <= x1) &&
                       (g0.y + rad >= y0) && (g0.y - rad <= y1);
            }
            const unsigned long long m = __ballot(pred);
            const int pre = __popcll(m & ((1ull << lane) - 1ull));
            if (pred) s_list[count + pre] = idx;
            count += (int)__popcll(m);
        }
        __syncthreads();

        // ---- composite
        const int px_i = tx*TS + (lane & (TS-1));
        const int py_i = ty*TS + (lane >> 3);
        const bool active = (px_i < width) && (py_i < height);
        const float px = (float)px_i + 0.5f;
        const float py = (float)py_i + 0.5f;

        float T = 1.0f, accr = 0.f, accg = 0.f, accb = 0.f, accd = 0.f, acca = 0.f;
        bool done = !active;

        for (int c = 0; c < count && !__all(done); c += 64) {
            const int cnt = min(64, count - c);
            if (lane < cnt) {
                const int idx = s_list[c + lane];
                s_g0[lane] = attrs[idx*3+0];
                s_g1[lane] = attrs[idx*3+1];
                s_g2[lane] = attrs[idx*3+2];
            }
            __syncthreads();
            if (!done) {
                for (int k = 0; k < cnt; k++) {
                    const float4 g0 = s_g0[k];
                    const float4 g1 = s_g1[k];
                    const float ddx = px - g0.x;
                    const float ddy = py - g0.y;
                    const float sigma = 0.5f*(g0.z*ddx*ddx + g1.x*ddy*ddy) + g0.w*ddx*ddy;
                    if (sigma < 0.0f) continue;
                    float alpha = g1.y * expf(-sigma);
                    if (alpha < ALPHA_MIN) continue;
                    alpha = fminf(alpha, ALPHA_MAX);
                    const float w = alpha * T;
                    const float4 g2 = s_g2[k];
                    accr += w * g2.x;
                    accg += w * g2.y;
                    accb += w * g2.z;
                    accd += w * g1.z;
                    acca += w;
                    T *= (1.0f - alpha);
                    if (T <= T_EPS) { done = true; break; }
                }
            }
            __syncthreads();
        }

        if (active) {
            const int pix = py_i * width + px_i;
            out[pix*4 + 0] = accr;
            out[pix*4 + 1] = accg;
            out[pix*4 + 2] = accb;
            out[pix*4 + 3] = accd / fmaxf(acca, 1e-10f);
            out[(size_t)P*4 + pix] = acca;
        }
    }
}

// ---------------- host-side launch ----------------
extern "C" void kernel_launch(void* const* d_in, const int* in_sizes, int n_in,
                              void* d_out, int out_size, void* d_ws, size_t ws_size,
                              hipStream_t stream) {
    const float* means   = (const float*)d_in[0];
    const float* opac    = (const float*)d_in[1];
    const float* scales  = (const float*)d_in[2];
    const float* quats   = (const float*)d_in[3];
    const float* sh0     = (const float*)d_in[4];
    const float* shN     = (const float*)d_in[5];
    const float* c2w     = (const float*)d_in[6];
    const float* Ks      = (const float*)d_in[7];
    const int*   wptr    = (const int*)d_in[8];
    const int*   hptr    = (const int*)d_in[9];

    const int N = in_sizes[0] / 3;
    const int P = out_size / 5;

    float4* attrs = (float4*)d_ws;               // 3*N float4
    float*  tz_u  = (float*)(attrs + 3*N);       // N floats
    int*    perm  = (int*)(tz_u + N);            // N ints

    const int gb = (N + 255) / 256;
    hipLaunchKernelGGL(preprocess_kernel, dim3(gb), dim3(256), 0, stream,
                       means, opac, scales, quats, sh0, shN, c2w, Ks, wptr, hptr,
                       attrs, tz_u, N);

    hipLaunchKernelGGL(sort_kernel, dim3(gb), dim3(256), N * sizeof(float), stream,
                       tz_u, perm, N);

    hipLaunchKernelGGL(raster_kernel, dim3(1024), dim3(64), N * sizeof(int), stream,
                       attrs, perm, (float*)d_out, N, P, wptr);
}

// Round 3
// 56.151 us; speedup vs baseline: 11.6060x; 1.9781x over previous
//
#include <hip/hip_runtime.h>
#include <math.h>

#define SH_C0f 0.28209479177387814f
#define SH_C1f 0.4886025119029199f
#define EPS2D 0.3f
#define NEAR_PLANE 0.01f
#define FAR_PLANE 1e10f
#define ALPHA_MIN (1.0f/255.0f)
#define ALPHA_MAX 0.999f
#define T_EPS 1e-4f
#define TS 8   // tile size (8x8 pixels, one wave per tile)

// ---------------- kernel 1: per-gaussian preprocess (inline 4x4 inverse) ---
__global__ void preprocess_kernel(
    const float* __restrict__ means, const float* __restrict__ opac_in,
    const float* __restrict__ scales, const float* __restrict__ quats,
    const float* __restrict__ sh0, const float* __restrict__ shN,
    const float* __restrict__ c2w, const float* __restrict__ Ks,
    const int* __restrict__ wptr, const int* __restrict__ hptr,
    float4* __restrict__ attrs, float* __restrict__ tz_arr, int N)
{
    int i = blockIdx.x * blockDim.x + threadIdx.x;
    if (i >= N) return;

    // ---- inline general 4x4 inverse of camtoworlds (rows 0..2 needed) ----
    float m[16];
    #pragma unroll
    for (int k = 0; k < 16; k++) m[k] = c2w[k];
    float inv[12];
    inv[0]  =  m[5]*m[10]*m[15] - m[5]*m[11]*m[14] - m[9]*m[6]*m[15] + m[9]*m[7]*m[14] + m[13]*m[6]*m[11] - m[13]*m[7]*m[10];
    inv[4]  = -m[4]*m[10]*m[15] + m[4]*m[11]*m[14] + m[8]*m[6]*m[15] - m[8]*m[7]*m[14] - m[12]*m[6]*m[11] + m[12]*m[7]*m[10];
    inv[8]  =  m[4]*m[9]*m[15]  - m[4]*m[11]*m[13] - m[8]*m[5]*m[15] + m[8]*m[7]*m[13] + m[12]*m[5]*m[11] - m[12]*m[7]*m[9];
    inv[1]  = -m[1]*m[10]*m[15] + m[1]*m[11]*m[14] + m[9]*m[2]*m[15] - m[9]*m[3]*m[14] - m[13]*m[2]*m[11] + m[13]*m[3]*m[10];
    inv[5]  =  m[0]*m[10]*m[15] - m[0]*m[11]*m[14] - m[8]*m[2]*m[15] + m[8]*m[3]*m[14] + m[12]*m[2]*m[11] - m[12]*m[3]*m[10];
    inv[9]  = -m[0]*m[9]*m[15]  + m[0]*m[11]*m[13] + m[8]*m[1]*m[15] - m[8]*m[3]*m[13] - m[12]*m[1]*m[11] + m[12]*m[3]*m[9];
    inv[2]  =  m[1]*m[6]*m[15]  - m[1]*m[7]*m[14]  - m[5]*m[2]*m[15] + m[5]*m[3]*m[14] + m[13]*m[2]*m[7]  - m[13]*m[3]*m[6];
    inv[6]  = -m[0]*m[6]*m[15]  + m[0]*m[7]*m[14]  + m[4]*m[2]*m[15] - m[4]*m[3]*m[14] - m[12]*m[2]*m[7]  + m[12]*m[3]*m[6];
    inv[10] =  m[0]*m[5]*m[15]  - m[0]*m[7]*m[13]  - m[4]*m[1]*m[15] + m[4]*m[3]*m[13] + m[12]*m[1]*m[7]  - m[12]*m[3]*m[5];
    inv[3]  = -m[1]*m[6]*m[11]  + m[1]*m[7]*m[10]  + m[5]*m[2]*m[11] - m[5]*m[3]*m[10] - m[9]*m[2]*m[7]   + m[9]*m[3]*m[6];
    inv[7]  =  m[0]*m[6]*m[11]  - m[0]*m[7]*m[10]  - m[4]*m[2]*m[11] + m[4]*m[3]*m[10] + m[8]*m[2]*m[7]   - m[8]*m[3]*m[6];
    inv[11] = -m[0]*m[5]*m[11]  + m[0]*m[7]*m[9]   + m[4]*m[1]*m[11] - m[4]*m[3]*m[9]  - m[8]*m[1]*m[7]   + m[8]*m[3]*m[5];
    {
        float inv12 = -m[4]*m[9]*m[14] + m[4]*m[10]*m[13] + m[8]*m[5]*m[14] - m[8]*m[6]*m[13] - m[12]*m[5]*m[10] + m[12]*m[6]*m[9];
        float det = m[0]*inv[0] + m[1]*inv[4] + m[2]*inv[8] + m[3]*inv12;
        float r = 1.0f / det;
        #pragma unroll
        for (int k = 0; k < 12; k++) inv[k] *= r;
    }
    const float W00 = inv[0], W01 = inv[1], W02 = inv[2],  t0 = inv[3];
    const float W10 = inv[4], W11 = inv[5], W12 = inv[6],  t1 = inv[7];
    const float W20 = inv[8], W21 = inv[9], W22 = inv[10], t2 = inv[11];

    const float fx = Ks[0], cx = Ks[2], fy = Ks[4], cy = Ks[5];
    const float width = (float)wptr[0], height = (float)hptr[0];

    const float mxx = means[i*3+0], myy = means[i*3+1], mzz = means[i*3+2];

    // view direction from camera position (camtoworlds[0,:3,3])
    const float cpx = m[3], cpy = m[7], cpz = m[11];
    float dx = mxx - cpx, dy = myy - cpy, dz = mzz - cpz;
    float dn = sqrtf(dx*dx + dy*dy + dz*dz);
    dx /= dn; dy /= dn; dz /= dn;

    // SH degree-1 color
    float col[3];
    #pragma unroll
    for (int c = 0; c < 3; c++) {
        float v = SH_C0f * sh0[i*3+c]
                + SH_C1f * (-dy * shN[i*9 + 0*3 + c] + dz * shN[i*9 + 1*3 + c] - dx * shN[i*9 + 2*3 + c])
                + 0.5f;
        col[c] = fmaxf(v, 0.0f);
    }

    // sigmoid opacity
    const float op = 1.0f / (1.0f + expf(-opac_in[i]));

    // quat -> R (normalized)
    float qw = quats[i*4+0], qx = quats[i*4+1], qy = quats[i*4+2], qz = quats[i*4+3];
    float qn = sqrtf(qw*qw + qx*qx + qy*qy + qz*qz);
    qw /= qn; qx /= qn; qy /= qn; qz /= qn;
    const float R00 = 1.f - 2.f*(qy*qy + qz*qz), R01 = 2.f*(qx*qy - qw*qz), R02 = 2.f*(qx*qz + qw*qy);
    const float R10 = 2.f*(qx*qy + qw*qz), R11 = 1.f - 2.f*(qx*qx + qz*qz), R12 = 2.f*(qy*qz - qw*qx);
    const float R20 = 2.f*(qx*qz - qw*qy), R21 = 2.f*(qy*qz + qw*qx), R22 = 1.f - 2.f*(qx*qx + qy*qy);

    const float sx = scales[i*3+0], sy = scales[i*3+1], sz = scales[i*3+2];
    const float M00 = R00*sx, M01 = R01*sy, M02 = R02*sz;
    const float M10 = R10*sx, M11 = R11*sy, M12 = R12*sz;
    const float M20 = R20*sx, M21 = R21*sy, M22 = R22*sz;

    // cov3d = M M^T (symmetric)
    const float S00 = M00*M00 + M01*M01 + M02*M02;
    const float S01 = M00*M10 + M01*M11 + M02*M12;
    const float S02 = M00*M20 + M01*M21 + M02*M22;
    const float S11 = M10*M10 + M11*M11 + M12*M12;
    const float S12 = M10*M20 + M11*M21 + M12*M22;
    const float S22 = M20*M20 + M21*M21 + M22*M22;

    // camera-space mean
    const float tcx = W00*mxx + W01*myy + W02*mzz + t0;
    const float tcy = W10*mxx + W11*myy + W12*mzz + t1;
    const float tcz = W20*mxx + W21*myy + W22*mzz + t2;
    const float rz = 1.0f / tcz;

    const float limx = 1.3f * (0.5f * width / fx);
    const float limy = 1.3f * (0.5f * height / fy);
    const float txz = fminf(fmaxf(tcx * rz, -limx), limx);
    const float tyz = fminf(fmaxf(tcy * rz, -limy), limy);

    // cov_cam = W3 S W3^T
    const float V00 = W00*S00 + W01*S01 + W02*S02;
    const float V01 = W00*S01 + W01*S11 + W02*S12;
    const float V02 = W00*S02 + W01*S12 + W02*S22;
    const float V10 = W10*S00 + W11*S01 + W12*S02;
    const float V11 = W10*S01 + W11*S11 + W12*S12;
    const float V12 = W10*S02 + W11*S12 + W12*S22;
    const float V20 = W20*S00 + W21*S01 + W22*S02;
    const float V21 = W20*S01 + W21*S11 + W22*S12;
    const float V22 = W20*S02 + W21*S12 + W22*S22;
    const float CC00 = V00*W00 + V01*W01 + V02*W02;
    const float CC01 = V00*W10 + V01*W11 + V02*W12;
    const float CC02 = V00*W20 + V01*W21 + V02*W22;
    const float CC11 = V10*W10 + V11*W11 + V12*W12;
    const float CC12 = V10*W20 + V11*W21 + V12*W22;
    const float CC22 = V20*W20 + V21*W21 + V22*W22;

    // J (2x3)
    const float j00 = fx * rz,  j02 = -fx * txz * rz;
    const float j11 = fy * rz,  j12 = -fy * tyz * rz;

    // cov2d = J CC J^T
    const float u0 = j00*CC00 + j02*CC02;
    const float u1 = j00*CC01 + j02*CC12;
    const float u2 = j00*CC02 + j02*CC22;
    const float v1 = j11*CC11 + j12*CC12;
    const float v2 = j11*CC12 + j12*CC22;
    const float c2d00 = u0*j00 + u2*j02;
    const float c2d01 = u1*j11 + u2*j12;
    const float c2d11 = v1*j11 + v2*j12;

    const float a  = c2d00 + EPS2D;
    const float bb = c2d01;
    const float cc = c2d11 + EPS2D;
    const float det = a*cc - bb*bb;
    const float det_safe = (det > 0.0f) ? det : 1.0f;
    const float invd = 1.0f / det_safe;

    const bool valid = (tcz > NEAR_PLANE) && (tcz < FAR_PLANE) && (det > 0.0f);

    // conservative cull radius: alpha >= 1/255 needs sigma <= ln(255*op);
    // sigma = 0.5 d^T Sigma^-1 d >= 0.5 |d|^2 / lambda_max(Sigma)
    float rad = 0.0f;
    if (valid && op >= ALPHA_MIN) {
        const float lmax = 0.5f*(a + cc) + sqrtf(fmaxf(0.f, 0.25f*(a - cc)*(a - cc) + bb*bb));
        const float sig_cut = logf(255.0f * op);
        rad = sqrtf(fmaxf(sig_cut, 0.0f) * 2.0f * lmax) * 1.001f + 0.5f;
    }

    const float mx2d = fx * tcx * rz + cx;
    const float my2d = fy * tcy * rz + cy;

    attrs[i*3+0] = make_float4(mx2d, my2d, cc * invd, -bb * invd);   // mx, my, A, B
    attrs[i*3+1] = make_float4(a * invd, op, tcz, rad);              // C, op, tz, rad
    attrs[i*3+2] = make_float4(col[0], col[1], col[2], 0.0f);       // r, g, b
    tz_arr[i] = tcz;
}

// ------- kernel 2: stable rank sort, ONE WAVE PER ELEMENT -> permutation ---
// rank(i) = #{ j : tz[j] < tz[i]  or  (tz[j] == tz[i] and j < i) }
__global__ __launch_bounds__(64) void sort_kernel(
    const float* __restrict__ tz, int* __restrict__ perm, int N)
{
    const int i = blockIdx.x;
    const int lane = threadIdx.x;
    const float k = tz[i];

    int rank = 0;
    // vectorized main loop: lane handles float4 group (lane + it*64)
    int j = lane * 4;
    const int Nv = N & ~3;
    for (; j + 3 < Nv; j += 256) {
        const float4 v = *reinterpret_cast<const float4*>(tz + j);
        rank += (v.x < k) || (v.x == k && (j + 0) < i);
        rank += (v.y < k) || (v.y == k && (j + 1) < i);
        rank += (v.z < k) || (v.z == k && (j + 2) < i);
        rank += (v.w < k) || (v.w == k && (j + 3) < i);
    }
    // scalar tail (N % 4 elements), handled by low lanes
    const int t = Nv + lane;
    if (t < N) {
        const float kj = tz[t];
        rank += (kj < k) || (kj == k && t < i);
    }

    #pragma unroll
    for (int off = 32; off > 0; off >>= 1) rank += __shfl_down(rank, off);
    if (lane == 0) perm[rank] = i;
}

// ---------------- kernel 3: tiled rasterize (1 wave per 8x8 tile) ---------
__global__ __launch_bounds__(64) void raster_kernel(
    const float4* __restrict__ attrs, const int* __restrict__ perm,
    float* __restrict__ out, int N, int P, const int* __restrict__ wptr)
{
    extern __shared__ int s_list[];           // N ints (dynamic)
    __shared__ float4 s_g0[64], s_g1[64], s_g2[64];

    const int width  = wptr[0];
    const int height = P / width;
    const int tilesX = (width  + TS - 1) / TS;
    const int tilesY = (height + TS - 1) / TS;
    const int nTiles = tilesX * tilesY;
    const int lane = threadIdx.x;

    for (int tile = blockIdx.x; tile < nTiles; tile += gridDim.x) {
        __syncthreads();   // protect s_list reuse across grid-stride iterations

        const int tx = tile % tilesX, ty = tile / tilesX;
        const float x0 = (float)(tx*TS) + 0.5f;
        const float x1 = (float)(min(tx*TS + TS - 1, width  - 1)) + 0.5f;
        const float y0 = (float)(ty*TS) + 0.5f;
        const float y1 = (float)(min(ty*TS + TS - 1, height - 1)) + 0.5f;

        // ---- build depth-ordered intersection list (wave ballot compaction)
        int count = 0;
        for (int base = 0; base < N; base += 64) {
            const int j = base + lane;
            bool pred = false;
            int idx = 0;
            if (j < N) {
                idx = perm[j];
                const float4 g0 = attrs[idx*3+0];
                const float4 g1 = attrs[idx*3+1];
                const float rad = g1.w;
                pred = (rad > 0.0f) &&
                       (g0.x + rad >= x0) && (g0.x - rad <= x1) &&
                       (g0.y + rad >= y0) && (g0.y - rad <= y1);
            }
            const unsigned long long m = __ballot(pred);
            const int pre = __popcll(m & ((1ull << lane) - 1ull));
            if (pred) s_list[count + pre] = idx;
            count += (int)__popcll(m);
        }
        __syncthreads();

        // ---- composite
        const int px_i = tx*TS + (lane & (TS-1));
        const int py_i = ty*TS + (lane >> 3);
        const bool active = (px_i < width) && (py_i < height);
        const float px = (float)px_i + 0.5f;
        const float py = (float)py_i + 0.5f;

        float T = 1.0f, accr = 0.f, accg = 0.f, accb = 0.f, accd = 0.f, acca = 0.f;
        bool done = !active;

        for (int c = 0; c < count && !__all(done); c += 64) {
            const int cnt = min(64, count - c);
            if (lane < cnt) {
                const int idx = s_list[c + lane];
                s_g0[lane] = attrs[idx*3+0];
                s_g1[lane] = attrs[idx*3+1];
                s_g2[lane] = attrs[idx*3+2];
            }
            __syncthreads();
            if (!done) {
                for (int k = 0; k < cnt; k++) {
                    const float4 g0 = s_g0[k];
                    const float4 g1 = s_g1[k];
                    const float ddx = px - g0.x;
                    const float ddy = py - g0.y;
                    const float sigma = 0.5f*(g0.z*ddx*ddx + g1.x*ddy*ddy) + g0.w*ddx*ddy;
                    if (sigma < 0.0f) continue;
                    float alpha = g1.y * expf(-sigma);
                    if (alpha < ALPHA_MIN) continue;
                    alpha = fminf(alpha, ALPHA_MAX);
                    const float w = alpha * T;
                    const float4 g2 = s_g2[k];
                    accr += w * g2.x;
                    accg += w * g2.y;
                    accb += w * g2.z;
                    accd += w * g1.z;
                    acca += w;
                    T *= (1.0f - alpha);
                    if (T <= T_EPS) { done = true; break; }
                }
            }
            __syncthreads();
        }

        if (active) {
            const int pix = py_i * width + px_i;
            out[pix*4 + 0] = accr;
            out[pix*4 + 1] = accg;
            out[pix*4 + 2] = accb;
            out[pix*4 + 3] = accd / fmaxf(acca, 1e-10f);
            out[(size_t)P*4 + pix] = acca;
        }
    }
}

// ---------------- host-side launch ----------------
extern "C" void kernel_launch(void* const* d_in, const int* in_sizes, int n_in,
                              void* d_out, int out_size, void* d_ws, size_t ws_size,
                              hipStream_t stream) {
    const float* means   = (const float*)d_in[0];
    const float* opac    = (const float*)d_in[1];
    const float* scales  = (const float*)d_in[2];
    const float* quats   = (const float*)d_in[3];
    const float* sh0     = (const float*)d_in[4];
    const float* shN     = (const float*)d_in[5];
    const float* c2w     = (const float*)d_in[6];
    const float* Ks      = (const float*)d_in[7];
    const int*   wptr    = (const int*)d_in[8];
    const int*   hptr    = (const int*)d_in[9];

    const int N = in_sizes[0] / 3;
    const int P = out_size / 5;

    float4* attrs = (float4*)d_ws;               // 3*N float4
    float*  tz_u  = (float*)(attrs + 3*N);       // N floats
    int*    perm  = (int*)(tz_u + N);            // N ints

    const int gb = (N + 255) / 256;
    hipLaunchKernelGGL(preprocess_kernel, dim3(gb), dim3(256), 0, stream,
                       means, opac, scales, quats, sh0, shN, c2w, Ks, wptr, hptr,
                       attrs, tz_u, N);

    hipLaunchKernelGGL(sort_kernel, dim3(N), dim3(64), 0, stream,
                       tz_u, perm, N);

    hipLaunchKernelGGL(raster_kernel, dim3(1024), dim3(64), N * sizeof(int), stream,
                       attrs, perm, (float*)d_out, N, P, wptr);
}

// Round 4
// 46.713 us; speedup vs baseline: 13.9510x; 1.2020x over previous
//
#include <hip/hip_runtime.h>
#include <math.h>

#define SH_C0f 0.28209479177387814f
#define SH_C1f 0.4886025119029199f
#define EPS2D 0.3f
#define NEAR_PLANE 0.01f
#define FAR_PLANE 1e10f
#define ALPHA_MIN (1.0f/255.0f)
#define ALPHA_MAX 0.999f
#define T_EPS 1e-4f
#define TS 8   // tile size (8x8 pixels, one wave per tile)

// ---------------- kernel 1: per-gaussian preprocess (inline 4x4 inverse) ---
__global__ void preprocess_kernel(
    const float* __restrict__ means, const float* __restrict__ opac_in,
    const float* __restrict__ scales, const float* __restrict__ quats,
    const float* __restrict__ sh0, const float* __restrict__ shN,
    const float* __restrict__ c2w, const float* __restrict__ Ks,
    const int* __restrict__ wptr, const int* __restrict__ hptr,
    float4* __restrict__ attrs, float* __restrict__ tz_arr, int N)
{
    int i = blockIdx.x * blockDim.x + threadIdx.x;
    if (i >= N) return;

    // ---- inline general 4x4 inverse of camtoworlds (rows 0..2 needed) ----
    float m[16];
    #pragma unroll
    for (int k = 0; k < 16; k++) m[k] = c2w[k];
    float inv[12];
    inv[0]  =  m[5]*m[10]*m[15] - m[5]*m[11]*m[14] - m[9]*m[6]*m[15] + m[9]*m[7]*m[14] + m[13]*m[6]*m[11] - m[13]*m[7]*m[10];
    inv[4]  = -m[4]*m[10]*m[15] + m[4]*m[11]*m[14] + m[8]*m[6]*m[15] - m[8]*m[7]*m[14] - m[12]*m[6]*m[11] + m[12]*m[7]*m[10];
    inv[8]  =  m[4]*m[9]*m[15]  - m[4]*m[11]*m[13] - m[8]*m[5]*m[15] + m[8]*m[7]*m[13] + m[12]*m[5]*m[11] - m[12]*m[7]*m[9];
    inv[1]  = -m[1]*m[10]*m[15] + m[1]*m[11]*m[14] + m[9]*m[2]*m[15] - m[9]*m[3]*m[14] - m[13]*m[2]*m[11] + m[13]*m[3]*m[10];
    inv[5]  =  m[0]*m[10]*m[15] - m[0]*m[11]*m[14] - m[8]*m[2]*m[15] + m[8]*m[3]*m[14] + m[12]*m[2]*m[11] - m[12]*m[3]*m[10];
    inv[9]  = -m[0]*m[9]*m[15]  + m[0]*m[11]*m[13] + m[8]*m[1]*m[15] - m[8]*m[3]*m[13] - m[12]*m[1]*m[11] + m[12]*m[3]*m[9];
    inv[2]  =  m[1]*m[6]*m[15]  - m[1]*m[7]*m[14]  - m[5]*m[2]*m[15] + m[5]*m[3]*m[14] + m[13]*m[2]*m[7]  - m[13]*m[3]*m[6];
    inv[6]  = -m[0]*m[6]*m[15]  + m[0]*m[7]*m[14]  + m[4]*m[2]*m[15] - m[4]*m[3]*m[14] - m[12]*m[2]*m[7]  + m[12]*m[3]*m[6];
    inv[10] =  m[0]*m[5]*m[15]  - m[0]*m[7]*m[13]  - m[4]*m[1]*m[15] + m[4]*m[3]*m[13] + m[12]*m[1]*m[7]  - m[12]*m[3]*m[5];
    inv[3]  = -m[1]*m[6]*m[11]  + m[1]*m[7]*m[10]  + m[5]*m[2]*m[11] - m[5]*m[3]*m[10] - m[9]*m[2]*m[7]   + m[9]*m[3]*m[6];
    inv[7]  =  m[0]*m[6]*m[11]  - m[0]*m[7]*m[10]  - m[4]*m[2]*m[11] + m[4]*m[3]*m[10] + m[8]*m[2]*m[7]   - m[8]*m[3]*m[6];
    inv[11] = -m[0]*m[5]*m[11]  + m[0]*m[7]*m[9]   + m[4]*m[1]*m[11] - m[4]*m[3]*m[9]  - m[8]*m[1]*m[7]   + m[8]*m[3]*m[5];
    {
        float inv12 = -m[4]*m[9]*m[14] + m[4]*m[10]*m[13] + m[8]*m[5]*m[14] - m[8]*m[6]*m[13] - m[12]*m[5]*m[10] + m[12]*m[6]*m[9];
        float det = m[0]*inv[0] + m[1]*inv[4] + m[2]*inv[8] + m[3]*inv12;
        float r = 1.0f / det;
        #pragma unroll
        for (int k = 0; k < 12; k++) inv[k] *= r;
    }
    const float W00 = inv[0], W01 = inv[1], W02 = inv[2],  t0 = inv[3];
    const float W10 = inv[4], W11 = inv[5], W12 = inv[6],  t1 = inv[7];
    const float W20 = inv[8], W21 = inv[9], W22 = inv[10], t2 = inv[11];

    const float fx = Ks[0], cx = Ks[2], fy = Ks[4], cy = Ks[5];
    const float width = (float)wptr[0], height = (float)hptr[0];

    const float mxx = means[i*3+0], myy = means[i*3+1], mzz = means[i*3+2];

    // view direction from camera position (camtoworlds[0,:3,3])
    const float cpx = m[3], cpy = m[7], cpz = m[11];
    float dx = mxx - cpx, dy = myy - cpy, dz = mzz - cpz;
    float dn = sqrtf(dx*dx + dy*dy + dz*dz);
    dx /= dn; dy /= dn; dz /= dn;

    // SH degree-1 color
    float col[3];
    #pragma unroll
    for (int c = 0; c < 3; c++) {
        float v = SH_C0f * sh0[i*3+c]
                + SH_C1f * (-dy * shN[i*9 + 0*3 + c] + dz * shN[i*9 + 1*3 + c] - dx * shN[i*9 + 2*3 + c])
                + 0.5f;
        col[c] = fmaxf(v, 0.0f);
    }

    // sigmoid opacity
    const float op = 1.0f / (1.0f + expf(-opac_in[i]));

    // quat -> R (normalized)
    float qw = quats[i*4+0], qx = quats[i*4+1], qy = quats[i*4+2], qz = quats[i*4+3];
    float qn = sqrtf(qw*qw + qx*qx + qy*qy + qz*qz);
    qw /= qn; qx /= qn; qy /= qn; qz /= qn;
    const float R00 = 1.f - 2.f*(qy*qy + qz*qz), R01 = 2.f*(qx*qy - qw*qz), R02 = 2.f*(qx*qz + qw*qy);
    const float R10 = 2.f*(qx*qy + qw*qz), R11 = 1.f - 2.f*(qx*qx + qz*qz), R12 = 2.f*(qy*qz - qw*qx);
    const float R20 = 2.f*(qx*qz - qw*qy), R21 = 2.f*(qy*qz + qw*qx), R22 = 1.f - 2.f*(qx*qx + qy*qy);

    const float sx = scales[i*3+0], sy = scales[i*3+1], sz = scales[i*3+2];
    const float M00 = R00*sx, M01 = R01*sy, M02 = R02*sz;
    const float M10 = R10*sx, M11 = R11*sy, M12 = R12*sz;
    const float M20 = R20*sx, M21 = R21*sy, M22 = R22*sz;

    // cov3d = M M^T (symmetric)
    const float S00 = M00*M00 + M01*M01 + M02*M02;
    const float S01 = M00*M10 + M01*M11 + M02*M12;
    const float S02 = M00*M20 + M01*M21 + M02*M22;
    const float S11 = M10*M10 + M11*M11 + M12*M12;
    const float S12 = M10*M20 + M11*M21 + M12*M22;
    const float S22 = M20*M20 + M21*M21 + M22*M22;

    // camera-space mean
    const float tcx = W00*mxx + W01*myy + W02*mzz + t0;
    const float tcy = W10*mxx + W11*myy + W12*mzz + t1;
    const float tcz = W20*mxx + W21*myy + W22*mzz + t2;
    const float rz = 1.0f / tcz;

    const float limx = 1.3f * (0.5f * width / fx);
    const float limy = 1.3f * (0.5f * height / fy);
    const float txz = fminf(fmaxf(tcx * rz, -limx), limx);
    const float tyz = fminf(fmaxf(tcy * rz, -limy), limy);

    // cov_cam = W3 S W3^T
    const float V00 = W00*S00 + W01*S01 + W02*S02;
    const float V01 = W00*S01 + W01*S11 + W02*S12;
    const float V02 = W00*S02 + W01*S12 + W02*S22;
    const float V10 = W10*S00 + W11*S01 + W12*S02;
    const float V11 = W10*S01 + W11*S11 + W12*S12;
    const float V12 = W10*S02 + W11*S12 + W12*S22;
    const float V20 = W20*S00 + W21*S01 + W22*S02;
    const float V21 = W20*S01 + W21*S11 + W22*S12;
    const float V22 = W20*S02 + W21*S12 + W22*S22;
    const float CC00 = V00*W00 + V01*W01 + V02*W02;
    const float CC01 = V00*W10 + V01*W11 + V02*W12;
    const float CC02 = V00*W20 + V01*W21 + V02*W22;
    const float CC11 = V10*W10 + V11*W11 + V12*W12;
    const float CC12 = V10*W20 + V11*W21 + V12*W22;
    const float CC22 = V20*W20 + V21*W21 + V22*W22;

    // J (2x3)
    const float j00 = fx * rz,  j02 = -fx * txz * rz;
    const float j11 = fy * rz,  j12 = -fy * tyz * rz;

    // cov2d = J CC J^T
    const float u0 = j00*CC00 + j02*CC02;
    const float u1 = j00*CC01 + j02*CC12;
    const float u2 = j00*CC02 + j02*CC22;
    const float v1 = j11*CC11 + j12*CC12;
    const float v2 = j11*CC12 + j12*CC22;
    const float c2d00 = u0*j00 + u2*j02;
    const float c2d01 = u1*j11 + u2*j12;
    const float c2d11 = v1*j11 + v2*j12;

    const float a  = c2d00 + EPS2D;
    const float bb = c2d01;
    const float cc = c2d11 + EPS2D;
    const float det = a*cc - bb*bb;
    const float det_safe = (det > 0.0f) ? det : 1.0f;
    const float invd = 1.0f / det_safe;

    const bool valid = (tcz > NEAR_PLANE) && (tcz < FAR_PLANE) && (det > 0.0f);

    // conservative cull radius: alpha >= 1/255 needs sigma <= ln(255*op);
    // sigma = 0.5 d^T Sigma^-1 d >= 0.5 |d|^2 / lambda_max(Sigma)
    float rad = 0.0f;
    if (valid && op >= ALPHA_MIN) {
        const float lmax = 0.5f*(a + cc) + sqrtf(fmaxf(0.f, 0.25f*(a - cc)*(a - cc) + bb*bb));
        const float sig_cut = logf(255.0f * op);
        rad = sqrtf(fmaxf(sig_cut, 0.0f) * 2.0f * lmax) * 1.001f + 0.5f;
    }

    const float mx2d = fx * tcx * rz + cx;
    const float my2d = fy * tcy * rz + cy;

    // store HALF conic coefficients (exact power-of-two scale):
    // sigma = (A/2) dx^2 + (C/2) dy^2 + B dx dy  ==  0.5*(A dx^2 + C dy^2) + B dx dy
    attrs[i*3+0] = make_float4(mx2d, my2d, 0.5f * cc * invd, -bb * invd);  // mx, my, A/2, B
    attrs[i*3+1] = make_float4(0.5f * a * invd, op, tcz, rad);             // C/2, op, tz, rad
    attrs[i*3+2] = make_float4(col[0], col[1], col[2], 0.0f);             // r, g, b
    tz_arr[i] = tcz;
}

// --- kernel 2: stable rank sort (one wave/element) + scatter to sorted order
// rank(i) = #{ j : tz[j] < tz[i]  or  (tz[j] == tz[i] and j < i) }
__global__ __launch_bounds__(64) void sort_scatter_kernel(
    const float* __restrict__ tz, const float4* __restrict__ attrs,
    float4* __restrict__ attrs_s, float4* __restrict__ bounds_s, int N)
{
    const int i = blockIdx.x;
    const int lane = threadIdx.x;
    const float k = tz[i];

    int rank = 0;
    int j = lane * 4;
    const int Nv = N & ~3;
    for (; j + 3 < Nv; j += 256) {
        const float4 v = *reinterpret_cast<const float4*>(tz + j);
        rank += (v.x < k) || (v.x == k && (j + 0) < i);
        rank += (v.y < k) || (v.y == k && (j + 1) < i);
        rank += (v.z < k) || (v.z == k && (j + 2) < i);
        rank += (v.w < k) || (v.w == k && (j + 3) < i);
    }
    const int t = Nv + lane;
    if (t < N) {
        const float kj = tz[t];
        rank += (kj < k) || (kj == k && t < i);
    }

    #pragma unroll
    for (int off = 32; off > 0; off >>= 1) rank += __shfl_down(rank, off);
    rank = __shfl(rank, 0);

    if (lane < 3) attrs_s[rank*3 + lane] = attrs[i*3 + lane];
    if (lane == 3) {
        const float4 g0 = attrs[i*3+0];
        const float4 g1 = attrs[i*3+1];
        bounds_s[rank] = make_float4(g0.x, g0.y, g1.w, 0.0f);   // mx, my, rad
    }
}

// ---------------- kernel 3: tiled rasterize (1 wave per 8x8 tile) ---------
__global__ __launch_bounds__(64) void raster_kernel(
    const float4* __restrict__ attrs_s, const float4* __restrict__ bounds_s,
    float* __restrict__ out, int N, int P, const int* __restrict__ wptr)
{
    extern __shared__ int s_list[];           // N ints (dynamic)
    __shared__ float4 s_g0[64], s_g1[64], s_g2[64];

    const int width  = wptr[0];
    const int height = P / width;
    const int tilesX = (width  + TS - 1) / TS;
    const int tilesY = (height + TS - 1) / TS;
    const int nTiles = tilesX * tilesY;
    const int lane = threadIdx.x;

    for (int tile = blockIdx.x; tile < nTiles; tile += gridDim.x) {
        __syncthreads();   // protect s_list reuse across grid-stride iterations

        const int tx = tile % tilesX, ty = tile / tilesX;
        const float x0 = (float)(tx*TS) + 0.5f;
        const float x1 = (float)(min(tx*TS + TS - 1, width  - 1)) + 0.5f;
        const float y0 = (float)(ty*TS) + 0.5f;
        const float y1 = (float)(min(ty*TS + TS - 1, height - 1)) + 0.5f;

        // ---- cull scan: coalesced linear stream over sorted bounds -------
        int count = 0;
        for (int base = 0; base < N; base += 64) {
            const int j = base + lane;
            bool pred = false;
            if (j < N) {
                const float4 b = bounds_s[j];          // mx, my, rad
                pred = (b.z > 0.0f) &&
                       (b.x + b.z >= x0) && (b.x - b.z <= x1) &&
                       (b.y + b.z >= y0) && (b.y - b.z <= y1);
            }
            const unsigned long long m = __ballot(pred);
            const int pre = __popcll(m & ((1ull << lane) - 1ull));
            if (pred) s_list[count + pre] = j;          // sorted position
            count += (int)__popcll(m);
        }
        __syncthreads();

        // ---- composite
        const int px_i = tx*TS + (lane & (TS-1));
        const int py_i = ty*TS + (lane >> 3);
        const bool active = (px_i < width) && (py_i < height);
        const float px = (float)px_i + 0.5f;
        const float py = (float)py_i + 0.5f;

        float T = 1.0f, accr = 0.f, accg = 0.f, accb = 0.f, accd = 0.f, acca = 0.f;
        bool done = !active;

        for (int c = 0; c < count && !__all(done); c += 64) {
            const int cnt = min(64, count - c);
            if (lane < cnt) {
                const int idx = s_list[c + lane];
                s_g0[lane] = attrs_s[idx*3+0];
                s_g1[lane] = attrs_s[idx*3+1];
                s_g2[lane] = attrs_s[idx*3+2];
            }
            __syncthreads();
            if (!done) {
                for (int k = 0; k < cnt; k++) {
                    const float4 g0 = s_g0[k];
                    const float4 g1 = s_g1[k];
                    const float ddx = px - g0.x;
                    const float ddy = py - g0.y;
                    const float sigma = g0.z*ddx*ddx + g1.x*ddy*ddy + g0.w*ddx*ddy;
                    if (sigma < 0.0f) continue;
                    float alpha = g1.y * expf(-sigma);
                    if (alpha < ALPHA_MIN) continue;
                    alpha = fminf(alpha, ALPHA_MAX);
                    const float w = alpha * T;
                    const float4 g2 = s_g2[k];
                    accr += w * g2.x;
                    accg += w * g2.y;
                    accb += w * g2.z;
                    accd += w * g1.z;
                    acca += w;
                    T *= (1.0f - alpha);
                    if (T <= T_EPS) { done = true; break; }
                }
            }
            __syncthreads();
        }

        if (active) {
            const int pix = py_i * width + px_i;
            out[pix*4 + 0] = accr;
            out[pix*4 + 1] = accg;
            out[pix*4 + 2] = accb;
            out[pix*4 + 3] = accd / fmaxf(acca, 1e-10f);
            out[(size_t)P*4 + pix] = acca;
        }
    }
}

// ---------------- host-side launch ----------------
extern "C" void kernel_launch(void* const* d_in, const int* in_sizes, int n_in,
                              void* d_out, int out_size, void* d_ws, size_t ws_size,
                              hipStream_t stream) {
    const float* means   = (const float*)d_in[0];
    const float* opac    = (const float*)d_in[1];
    const float* scales  = (const float*)d_in[2];
    const float* quats   = (const float*)d_in[3];
    const float* sh0     = (const float*)d_in[4];
    const float* shN     = (const float*)d_in[5];
    const float* c2w     = (const float*)d_in[6];
    const float* Ks      = (const float*)d_in[7];
    const int*   wptr    = (const int*)d_in[8];
    const int*   hptr    = (const int*)d_in[9];

    const int N = in_sizes[0] / 3;
    const int P = out_size / 5;

    float4* attrs    = (float4*)d_ws;                  // 3*N float4
    float4* attrs_s  = attrs + 3*N;                    // 3*N float4 (sorted)
    float4* bounds_s = attrs_s + 3*N;                  // N float4 (sorted mx,my,rad)
    float*  tz_u     = (float*)(bounds_s + N);         // N floats

    const int gb = (N + 255) / 256;
    hipLaunchKernelGGL(preprocess_kernel, dim3(gb), dim3(256), 0, stream,
                       means, opac, scales, quats, sh0, shN, c2w, Ks, wptr, hptr,
                       attrs, tz_u, N);

    hipLaunchKernelGGL(sort_scatter_kernel, dim3(N), dim3(64), 0, stream,
                       tz_u, attrs, attrs_s, bounds_s, N);

    hipLaunchKernelGGL(raster_kernel, dim3(1024), dim3(64), N * sizeof(int), stream,
                       attrs_s, bounds_s, (float*)d_out, N, P, wptr);
}

// Round 5
// 36.119 us; speedup vs baseline: 18.0428x; 1.2933x over previous
//
#include <hip/hip_runtime.h>
#include <math.h>

#define SH_C0f 0.28209479177387814f
#define SH_C1f 0.4886025119029199f
#define EPS2D 0.3f
#define NEAR_PLANE 0.01f
#define FAR_PLANE 1e10f
#define ALPHA_MIN (1.0f/255.0f)
#define ALPHA_MAX 0.999f
#define T_EPS 1e-4f
#define TS 8   // tile size (8x8 pixels, one wave per tile)

// ---------------- kernel 1: per-gaussian preprocess (inline 4x4 inverse) ---
__global__ void preprocess_kernel(
    const float* __restrict__ means, const float* __restrict__ opac_in,
    const float* __restrict__ scales, const float* __restrict__ quats,
    const float* __restrict__ sh0, const float* __restrict__ shN,
    const float* __restrict__ c2w, const float* __restrict__ Ks,
    const int* __restrict__ wptr, const int* __restrict__ hptr,
    float4* __restrict__ attrs, float* __restrict__ tz_arr, int N)
{
    int i = blockIdx.x * blockDim.x + threadIdx.x;
    if (i >= N) return;

    // ---- inline general 4x4 inverse of camtoworlds (rows 0..2 needed) ----
    float m[16];
    #pragma unroll
    for (int k = 0; k < 16; k++) m[k] = c2w[k];
    float inv[12];
    inv[0]  =  m[5]*m[10]*m[15] - m[5]*m[11]*m[14] - m[9]*m[6]*m[15] + m[9]*m[7]*m[14] + m[13]*m[6]*m[11] - m[13]*m[7]*m[10];
    inv[4]  = -m[4]*m[10]*m[15] + m[4]*m[11]*m[14] + m[8]*m[6]*m[15] - m[8]*m[7]*m[14] - m[12]*m[6]*m[11] + m[12]*m[7]*m[10];
    inv[8]  =  m[4]*m[9]*m[15]  - m[4]*m[11]*m[13] - m[8]*m[5]*m[15] + m[8]*m[7]*m[13] + m[12]*m[5]*m[11] - m[12]*m[7]*m[9];
    inv[1]  = -m[1]*m[10]*m[15] + m[1]*m[11]*m[14] + m[9]*m[2]*m[15] - m[9]*m[3]*m[14] - m[13]*m[2]*m[11] + m[13]*m[3]*m[10];
    inv[5]  =  m[0]*m[10]*m[15] - m[0]*m[11]*m[14] - m[8]*m[2]*m[15] + m[8]*m[3]*m[14] + m[12]*m[2]*m[11] - m[12]*m[3]*m[10];
    inv[9]  = -m[0]*m[9]*m[15]  + m[0]*m[11]*m[13] + m[8]*m[1]*m[15] - m[8]*m[3]*m[13] - m[12]*m[1]*m[11] + m[12]*m[3]*m[9];
    inv[2]  =  m[1]*m[6]*m[15]  - m[1]*m[7]*m[14]  - m[5]*m[2]*m[15] + m[5]*m[3]*m[14] + m[13]*m[2]*m[7]  - m[13]*m[3]*m[6];
    inv[6]  = -m[0]*m[6]*m[15]  + m[0]*m[7]*m[14]  + m[4]*m[2]*m[15] - m[4]*m[3]*m[14] - m[12]*m[2]*m[7]  + m[12]*m[3]*m[6];
    inv[10] =  m[0]*m[5]*m[15]  - m[0]*m[7]*m[13]  - m[4]*m[1]*m[15] + m[4]*m[3]*m[13] + m[12]*m[1]*m[7]  - m[12]*m[3]*m[5];
    inv[3]  = -m[1]*m[6]*m[11]  + m[1]*m[7]*m[10]  + m[5]*m[2]*m[11] - m[5]*m[3]*m[10] - m[9]*m[2]*m[7]   + m[9]*m[3]*m[6];
    inv[7]  =  m[0]*m[6]*m[11]  - m[0]*m[7]*m[10]  - m[4]*m[2]*m[11] + m[4]*m[3]*m[10] + m[8]*m[2]*m[7]   - m[8]*m[3]*m[6];
    inv[11] = -m[0]*m[5]*m[11]  + m[0]*m[7]*m[9]   + m[4]*m[1]*m[11] - m[4]*m[3]*m[9]  - m[8]*m[1]*m[7]   + m[8]*m[3]*m[5];
    {
        float inv12 = -m[4]*m[9]*m[14] + m[4]*m[10]*m[13] + m[8]*m[5]*m[14] - m[8]*m[6]*m[13] - m[12]*m[5]*m[10] + m[12]*m[6]*m[9];
        float det = m[0]*inv[0] + m[1]*inv[4] + m[2]*inv[8] + m[3]*inv12;
        float r = 1.0f / det;
        #pragma unroll
        for (int k = 0; k < 12; k++) inv[k] *= r;
    }
    const float W00 = inv[0], W01 = inv[1], W02 = inv[2],  t0 = inv[3];
    const float W10 = inv[4], W11 = inv[5], W12 = inv[6],  t1 = inv[7];
    const float W20 = inv[8], W21 = inv[9], W22 = inv[10], t2 = inv[11];

    const float fx = Ks[0], cx = Ks[2], fy = Ks[4], cy = Ks[5];
    const float width = (float)wptr[0], height = (float)hptr[0];

    const float mxx = means[i*3+0], myy = means[i*3+1], mzz = means[i*3+2];

    // view direction from camera position (camtoworlds[0,:3,3])
    const float cpx = m[3], cpy = m[7], cpz = m[11];
    float dx = mxx - cpx, dy = myy - cpy, dz = mzz - cpz;
    float dn = sqrtf(dx*dx + dy*dy + dz*dz);
    dx /= dn; dy /= dn; dz /= dn;

    // SH degree-1 color
    float col[3];
    #pragma unroll
    for (int c = 0; c < 3; c++) {
        float v = SH_C0f * sh0[i*3+c]
                + SH_C1f * (-dy * shN[i*9 + 0*3 + c] + dz * shN[i*9 + 1*3 + c] - dx * shN[i*9 + 2*3 + c])
                + 0.5f;
        col[c] = fmaxf(v, 0.0f);
    }

    // sigmoid opacity
    const float op = 1.0f / (1.0f + expf(-opac_in[i]));

    // quat -> R (normalized)
    float qw = quats[i*4+0], qx = quats[i*4+1], qy = quats[i*4+2], qz = quats[i*4+3];
    float qn = sqrtf(qw*qw + qx*qx + qy*qy + qz*qz);
    qw /= qn; qx /= qn; qy /= qn; qz /= qn;
    const float R00 = 1.f - 2.f*(qy*qy + qz*qz), R01 = 2.f*(qx*qy - qw*qz), R02 = 2.f*(qx*qz + qw*qy);
    const float R10 = 2.f*(qx*qy + qw*qz), R11 = 1.f - 2.f*(qx*qx + qz*qz), R12 = 2.f*(qy*qz - qw*qx);
    const float R20 = 2.f*(qx*qz - qw*qy), R21 = 2.f*(qy*qz + qw*qx), R22 = 1.f - 2.f*(qx*qx + qy*qy);

    const float sx = scales[i*3+0], sy = scales[i*3+1], sz = scales[i*3+2];
    const float M00 = R00*sx, M01 = R01*sy, M02 = R02*sz;
    const float M10 = R10*sx, M11 = R11*sy, M12 = R12*sz;
    const float M20 = R20*sx, M21 = R21*sy, M22 = R22*sz;

    // cov3d = M M^T (symmetric)
    const float S00 = M00*M00 + M01*M01 + M02*M02;
    const float S01 = M00*M10 + M01*M11 + M02*M12;
    const float S02 = M00*M20 + M01*M21 + M02*M22;
    const float S11 = M10*M10 + M11*M11 + M12*M12;
    const float S12 = M10*M20 + M11*M21 + M12*M22;
    const float S22 = M20*M20 + M21*M21 + M22*M22;

    // camera-space mean
    const float tcx = W00*mxx + W01*myy + W02*mzz + t0;
    const float tcy = W10*mxx + W11*myy + W12*mzz + t1;
    const float tcz = W20*mxx + W21*myy + W22*mzz + t2;
    const float rz = 1.0f / tcz;

    const float limx = 1.3f * (0.5f * width / fx);
    const float limy = 1.3f * (0.5f * height / fy);
    const float txz = fminf(fmaxf(tcx * rz, -limx), limx);
    const float tyz = fminf(fmaxf(tcy * rz, -limy), limy);

    // cov_cam = W3 S W3^T
    const float V00 = W00*S00 + W01*S01 + W02*S02;
    const float V01 = W00*S01 + W01*S11 + W02*S12;
    const float V02 = W00*S02 + W01*S12 + W02*S22;
    const float V10 = W10*S00 + W11*S01 + W12*S02;
    const float V11 = W10*S01 + W11*S11 + W12*S12;
    const float V12 = W10*S02 + W11*S12 + W12*S22;
    const float V20 = W20*S00 + W21*S01 + W22*S02;
    const float V21 = W20*S01 + W21*S11 + W22*S12;
    const float V22 = W20*S02 + W21*S12 + W22*S22;
    const float CC00 = V00*W00 + V01*W01 + V02*W02;
    const float CC01 = V00*W10 + V01*W11 + V02*W12;
    const float CC02 = V00*W20 + V01*W21 + V02*W22;
    const float CC11 = V10*W10 + V11*W11 + V12*W12;
    const float CC12 = V10*W20 + V11*W21 + V12*W22;
    const float CC22 = V20*W20 + V21*W21 + V22*W22;

    // J (2x3)
    const float j00 = fx * rz,  j02 = -fx * txz * rz;
    const float j11 = fy * rz,  j12 = -fy * tyz * rz;

    // cov2d = J CC J^T
    const float u0 = j00*CC00 + j02*CC02;
    const float u1 = j00*CC01 + j02*CC12;
    const float u2 = j00*CC02 + j02*CC22;
    const float v1 = j11*CC11 + j12*CC12;
    const float v2 = j11*CC12 + j12*CC22;
    const float c2d00 = u0*j00 + u2*j02;
    const float c2d01 = u1*j11 + u2*j12;
    const float c2d11 = v1*j11 + v2*j12;

    const float a  = c2d00 + EPS2D;
    const float bb = c2d01;
    const float cc = c2d11 + EPS2D;
    const float det = a*cc - bb*bb;
    const float det_safe = (det > 0.0f) ? det : 1.0f;
    const float invd = 1.0f / det_safe;

    const bool valid = (tcz > NEAR_PLANE) && (tcz < FAR_PLANE) && (det > 0.0f);

    // conservative cull radius: alpha >= 1/255 needs sigma <= ln(255*op);
    // sigma = 0.5 d^T Sigma^-1 d >= 0.5 |d|^2 / lambda_max(Sigma)
    float rad = 0.0f;
    if (valid && op >= ALPHA_MIN) {
        const float lmax = 0.5f*(a + cc) + sqrtf(fmaxf(0.f, 0.25f*(a - cc)*(a - cc) + bb*bb));
        const float sig_cut = logf(255.0f * op);
        rad = sqrtf(fmaxf(sig_cut, 0.0f) * 2.0f * lmax) * 1.001f + 0.5f;
    }

    const float mx2d = fx * tcx * rz + cx;
    const float my2d = fy * tcy * rz + cy;

    // store HALF conic coefficients (exact power-of-two scale):
    // sigma = (A/2) dx^2 + (C/2) dy^2 + B dx dy  ==  0.5*(A dx^2 + C dy^2) + B dx dy
    attrs[i*3+0] = make_float4(mx2d, my2d, 0.5f * cc * invd, -bb * invd);  // mx, my, A/2, B
    attrs[i*3+1] = make_float4(0.5f * a * invd, op, tcz, rad);             // C/2, op, tz, rad
    attrs[i*3+2] = make_float4(col[0], col[1], col[2], 0.0f);             // r, g, b
    tz_arr[i] = tcz;
}

// --- kernel 2: stable rank sort (one wave/element) + scatter to sorted order
// rank(i) = #{ j : tz[j] < tz[i]  or  (tz[j] == tz[i] and j < i) }
__global__ __launch_bounds__(64) void sort_scatter_kernel(
    const float* __restrict__ tz, const float4* __restrict__ attrs,
    float4* __restrict__ attrs_s, float4* __restrict__ bounds_s, int N)
{
    const int i = blockIdx.x;
    const int lane = threadIdx.x;
    const float k = tz[i];

    int rank = 0;
    int j = lane * 4;
    const int Nv = N & ~3;
    for (; j + 3 < Nv; j += 256) {
        const float4 v = *reinterpret_cast<const float4*>(tz + j);
        rank += (v.x < k) || (v.x == k && (j + 0) < i);
        rank += (v.y < k) || (v.y == k && (j + 1) < i);
        rank += (v.z < k) || (v.z == k && (j + 2) < i);
        rank += (v.w < k) || (v.w == k && (j + 3) < i);
    }
    const int t = Nv + lane;
    if (t < N) {
        const float kj = tz[t];
        rank += (kj < k) || (kj == k && t < i);
    }

    #pragma unroll
    for (int off = 32; off > 0; off >>= 1) rank += __shfl_down(rank, off);
    rank = __shfl(rank, 0);

    if (lane < 3) attrs_s[rank*3 + lane] = attrs[i*3 + lane];
    if (lane == 3) {
        const float4 g0 = attrs[i*3+0];
        const float4 g1 = attrs[i*3+1];
        bounds_s[rank] = make_float4(g0.x, g0.y, g1.w, 0.0f);   // mx, my, rad
    }
}

// ---------------- kernel 3: tiled rasterize (1 wave per 8x8 tile) ---------
// Branchless, 4-wide batched composite: LDS reads batched, 4 independent
// sigma/exp chains in flight, only the T-recurrence serial.
__global__ __launch_bounds__(64) void raster_kernel(
    const float4* __restrict__ attrs_s, const float4* __restrict__ bounds_s,
    float* __restrict__ out, int N, int P, const int* __restrict__ wptr)
{
    extern __shared__ int s_list[];           // N ints (dynamic)
    __shared__ float4 s_g0[64], s_g1[64], s_g2[64];

    const int width  = wptr[0];
    const int height = P / width;
    const int tilesX = (width  + TS - 1) / TS;
    const int tilesY = (height + TS - 1) / TS;
    const int nTiles = tilesX * tilesY;
    const int lane = threadIdx.x;

    for (int tile = blockIdx.x; tile < nTiles; tile += gridDim.x) {
        __syncthreads();   // protect s_list reuse across grid-stride iterations

        const int tx = tile % tilesX, ty = tile / tilesX;
        const float x0 = (float)(tx*TS) + 0.5f;
        const float x1 = (float)(min(tx*TS + TS - 1, width  - 1)) + 0.5f;
        const float y0 = (float)(ty*TS) + 0.5f;
        const float y1 = (float)(min(ty*TS + TS - 1, height - 1)) + 0.5f;

        // ---- cull scan: coalesced linear stream over sorted bounds -------
        int count = 0;
        #pragma unroll 4
        for (int base = 0; base < N; base += 64) {
            const int j = base + lane;
            bool pred = false;
            if (j < N) {
                const float4 b = bounds_s[j];          // mx, my, rad
                pred = (b.z > 0.0f) &&
                       (b.x + b.z >= x0) && (b.x - b.z <= x1) &&
                       (b.y + b.z >= y0) && (b.y - b.z <= y1);
            }
            const unsigned long long m = __ballot(pred);
            const int pre = __popcll(m & ((1ull << lane) - 1ull));
            if (pred) s_list[count + pre] = j;          // sorted position
            count += (int)__popcll(m);
        }
        __syncthreads();

        // ---- composite (branchless, 4-wide batched) ----------------------
        const int px_i = tx*TS + (lane & (TS-1));
        const int py_i = ty*TS + (lane >> 3);
        const bool active = (px_i < width) && (py_i < height);
        const float px = (float)px_i + 0.5f;
        const float py = (float)py_i + 0.5f;

        float T = active ? 1.0f : 0.0f;      // inactive lanes: all weights 0
        float accr = 0.f, accg = 0.f, accb = 0.f, accd = 0.f, acca = 0.f;

        for (int c = 0; c < count && !__all(T <= T_EPS); c += 64) {
            const int cnt = min(64, count - c);
            if (lane < cnt) {
                const int idx = s_list[c + lane];
                s_g0[lane] = attrs_s[idx*3+0];
                s_g1[lane] = attrs_s[idx*3+1];
                s_g2[lane] = attrs_s[idx*3+2];
            }
            __syncthreads();

            for (int k = 0; k < cnt; k += 4) {
                float4 G0[4], G1[4], G2[4];
                #pragma unroll
                for (int u = 0; u < 4; u++) {
                    G0[u] = s_g0[k+u];     // in-bounds: array is 64, k+3 <= 63
                    G1[u] = s_g1[k+u];
                    G2[u] = s_g2[k+u];
                }
                float al[4];
                #pragma unroll
                for (int u = 0; u < 4; u++) {
                    const float ddx = px - G0[u].x;
                    const float ddy = py - G0[u].y;
                    const float sg = G0[u].z*ddx*ddx + G1[u].x*ddy*ddy + G0[u].w*ddx*ddy;
                    float a = G1[u].y * expf(-sg);
                    a = ((sg >= 0.0f) && (a >= ALPHA_MIN)) ? fminf(a, ALPHA_MAX) : 0.0f;
                    al[u] = (k + u < cnt) ? a : 0.0f;   // tail: stale LDS -> 0
                }
                #pragma unroll
                for (int u = 0; u < 4; u++) {
                    const float w = (T > T_EPS) ? al[u] * T : 0.0f;
                    accr += w * G2[u].x;
                    accg += w * G2[u].y;
                    accb += w * G2[u].z;
                    accd += w * G1[u].z;
                    acca += w;
                    T *= (1.0f - al[u]);
                }
                if (__all(T <= T_EPS)) break;
            }
            __syncthreads();
        }

        if (active) {
            const int pix = py_i * width + px_i;
            out[pix*4 + 0] = accr;
            out[pix*4 + 1] = accg;
            out[pix*4 + 2] = accb;
            out[pix*4 + 3] = accd / fmaxf(acca, 1e-10f);
            out[(size_t)P*4 + pix] = acca;
        }
    }
}

// ---------------- host-side launch ----------------
extern "C" void kernel_launch(void* const* d_in, const int* in_sizes, int n_in,
                              void* d_out, int out_size, void* d_ws, size_t ws_size,
                              hipStream_t stream) {
    const float* means   = (const float*)d_in[0];
    const float* opac    = (const float*)d_in[1];
    const float* scales  = (const float*)d_in[2];
    const float* quats   = (const float*)d_in[3];
    const float* sh0     = (const float*)d_in[4];
    const float* shN     = (const float*)d_in[5];
    const float* c2w     = (const float*)d_in[6];
    const float* Ks      = (const float*)d_in[7];
    const int*   wptr    = (const int*)d_in[8];
    const int*   hptr    = (const int*)d_in[9];

    const int N = in_sizes[0] / 3;
    const int P = out_size / 5;

    float4* attrs    = (float4*)d_ws;                  // 3*N float4
    float4* attrs_s  = attrs + 3*N;                    // 3*N float4 (sorted)
    float4* bounds_s = attrs_s + 3*N;                  // N float4 (sorted mx,my,rad)
    float*  tz_u     = (float*)(bounds_s + N);         // N floats

    const int gb = (N + 255) / 256;
    hipLaunchKernelGGL(preprocess_kernel, dim3(gb), dim3(256), 0, stream,
                       means, opac, scales, quats, sh0, shN, c2w, Ks, wptr, hptr,
                       attrs, tz_u, N);

    hipLaunchKernelGGL(sort_scatter_kernel, dim3(N), dim3(64), 0, stream,
                       tz_u, attrs, attrs_s, bounds_s, N);

    hipLaunchKernelGGL(raster_kernel, dim3(1024), dim3(64), N * sizeof(int), stream,
                       attrs_s, bounds_s, (float*)d_out, N, P, wptr);
}

// Round 6
// 26.789 us; speedup vs baseline: 24.3268x; 1.3483x over previous
//
#include <hip/hip_runtime.h>
#include <math.h>

#define SH_C0f 0.28209479177387814f
#define SH_C1f 0.4886025119029199f
#define EPS2D 0.3f
#define NEAR_PLANE 0.01f
#define FAR_PLANE 1e10f
#define ALPHA_MIN (1.0f/255.0f)
#define ALPHA_MAX 0.999f
#define T_EPS 1e-4f
#define TS 8   // tile size (8x8 pixels)
#define NW 4   // waves per raster block (list segments)

// ---------------- kernel 1: per-gaussian preprocess (inline 4x4 inverse) ---
__global__ void preprocess_kernel(
    const float* __restrict__ means, const float* __restrict__ opac_in,
    const float* __restrict__ scales, const float* __restrict__ quats,
    const float* __restrict__ sh0, const float* __restrict__ shN,
    const float* __restrict__ c2w, const float* __restrict__ Ks,
    const int* __restrict__ wptr, const int* __restrict__ hptr,
    float4* __restrict__ attrs, float* __restrict__ tz_arr, int N)
{
    int i = blockIdx.x * blockDim.x + threadIdx.x;
    if (i >= N) return;

    // ---- inline general 4x4 inverse of camtoworlds (rows 0..2 needed) ----
    float m[16];
    #pragma unroll
    for (int k = 0; k < 16; k++) m[k] = c2w[k];
    float inv[12];
    inv[0]  =  m[5]*m[10]*m[15] - m[5]*m[11]*m[14] - m[9]*m[6]*m[15] + m[9]*m[7]*m[14] + m[13]*m[6]*m[11] - m[13]*m[7]*m[10];
    inv[4]  = -m[4]*m[10]*m[15] + m[4]*m[11]*m[14] + m[8]*m[6]*m[15] - m[8]*m[7]*m[14] - m[12]*m[6]*m[11] + m[12]*m[7]*m[10];
    inv[8]  =  m[4]*m[9]*m[15]  - m[4]*m[11]*m[13] - m[8]*m[5]*m[15] + m[8]*m[7]*m[13] + m[12]*m[5]*m[11] - m[12]*m[7]*m[9];
    inv[1]  = -m[1]*m[10]*m[15] + m[1]*m[11]*m[14] + m[9]*m[2]*m[15] - m[9]*m[3]*m[14] - m[13]*m[2]*m[11] + m[13]*m[3]*m[10];
    inv[5]  =  m[0]*m[10]*m[15] - m[0]*m[11]*m[14] - m[8]*m[2]*m[15] + m[8]*m[3]*m[14] + m[12]*m[2]*m[11] - m[12]*m[3]*m[10];
    inv[9]  = -m[0]*m[9]*m[15]  + m[0]*m[11]*m[13] + m[8]*m[1]*m[15] - m[8]*m[3]*m[13] - m[12]*m[1]*m[11] + m[12]*m[3]*m[9];
    inv[2]  =  m[1]*m[6]*m[15]  - m[1]*m[7]*m[14]  - m[5]*m[2]*m[15] + m[5]*m[3]*m[14] + m[13]*m[2]*m[7]  - m[13]*m[3]*m[6];
    inv[6]  = -m[0]*m[6]*m[15]  + m[0]*m[7]*m[14]  + m[4]*m[2]*m[15] - m[4]*m[3]*m[14] - m[12]*m[2]*m[7]  + m[12]*m[3]*m[6];
    inv[10] =  m[0]*m[5]*m[15]  - m[0]*m[7]*m[13]  - m[4]*m[1]*m[15] + m[4]*m[3]*m[13] + m[12]*m[1]*m[7]  - m[12]*m[3]*m[5];
    inv[3]  = -m[1]*m[6]*m[11]  + m[1]*m[7]*m[10]  + m[5]*m[2]*m[11] - m[5]*m[3]*m[10] - m[9]*m[2]*m[7]   + m[9]*m[3]*m[6];
    inv[7]  =  m[0]*m[6]*m[11]  - m[0]*m[7]*m[10]  - m[4]*m[2]*m[11] + m[4]*m[3]*m[10] + m[8]*m[2]*m[7]   - m[8]*m[3]*m[6];
    inv[11] = -m[0]*m[5]*m[11]  + m[0]*m[7]*m[9]   + m[4]*m[1]*m[11] - m[4]*m[3]*m[9]  - m[8]*m[1]*m[7]   + m[8]*m[3]*m[5];
    {
        float inv12 = -m[4]*m[9]*m[14] + m[4]*m[10]*m[13] + m[8]*m[5]*m[14] - m[8]*m[6]*m[13] - m[12]*m[5]*m[10] + m[12]*m[6]*m[9];
        float det = m[0]*inv[0] + m[1]*inv[4] + m[2]*inv[8] + m[3]*inv12;
        float r = 1.0f / det;
        #pragma unroll
        for (int k = 0; k < 12; k++) inv[k] *= r;
    }
    const float W00 = inv[0], W01 = inv[1], W02 = inv[2],  t0 = inv[3];
    const float W10 = inv[4], W11 = inv[5], W12 = inv[6],  t1 = inv[7];
    const float W20 = inv[8], W21 = inv[9], W22 = inv[10], t2 = inv[11];

    const float fx = Ks[0], cx = Ks[2], fy = Ks[4], cy = Ks[5];
    const float width = (float)wptr[0], height = (float)hptr[0];

    const float mxx = means[i*3+0], myy = means[i*3+1], mzz = means[i*3+2];

    // view direction from camera position (camtoworlds[0,:3,3])
    const float cpx = m[3], cpy = m[7], cpz = m[11];
    float dx = mxx - cpx, dy = myy - cpy, dz = mzz - cpz;
    float dn = sqrtf(dx*dx + dy*dy + dz*dz);
    dx /= dn; dy /= dn; dz /= dn;

    // SH degree-1 color
    float col[3];
    #pragma unroll
    for (int c = 0; c < 3; c++) {
        float v = SH_C0f * sh0[i*3+c]
                + SH_C1f * (-dy * shN[i*9 + 0*3 + c] + dz * shN[i*9 + 1*3 + c] - dx * shN[i*9 + 2*3 + c])
                + 0.5f;
        col[c] = fmaxf(v, 0.0f);
    }

    // sigmoid opacity
    const float op = 1.0f / (1.0f + expf(-opac_in[i]));

    // quat -> R (normalized)
    float qw = quats[i*4+0], qx = quats[i*4+1], qy = quats[i*4+2], qz = quats[i*4+3];
    float qn = sqrtf(qw*qw + qx*qx + qy*qy + qz*qz);
    qw /= qn; qx /= qn; qy /= qn; qz /= qn;
    const float R00 = 1.f - 2.f*(qy*qy + qz*qz), R01 = 2.f*(qx*qy - qw*qz), R02 = 2.f*(qx*qz + qw*qy);
    const float R10 = 2.f*(qx*qy + qw*qz), R11 = 1.f - 2.f*(qx*qx + qz*qz), R12 = 2.f*(qy*qz - qw*qx);
    const float R20 = 2.f*(qx*qz - qw*qy), R21 = 2.f*(qy*qz + qw*qx), R22 = 1.f - 2.f*(qx*qx + qy*qy);

    const float sx = scales[i*3+0], sy = scales[i*3+1], sz = scales[i*3+2];
    const float M00 = R00*sx, M01 = R01*sy, M02 = R02*sz;
    const float M10 = R10*sx, M11 = R11*sy, M12 = R12*sz;
    const float M20 = R20*sx, M21 = R21*sy, M22 = R22*sz;

    // cov3d = M M^T (symmetric)
    const float S00 = M00*M00 + M01*M01 + M02*M02;
    const float S01 = M00*M10 + M01*M11 + M02*M12;
    const float S02 = M00*M20 + M01*M21 + M02*M22;
    const float S11 = M10*M10 + M11*M11 + M12*M12;
    const float S12 = M10*M20 + M11*M21 + M12*M22;
    const float S22 = M20*M20 + M21*M21 + M22*M22;

    // camera-space mean
    const float tcx = W00*mxx + W01*myy + W02*mzz + t0;
    const float tcy = W10*mxx + W11*myy + W12*mzz + t1;
    const float tcz = W20*mxx + W21*myy + W22*mzz + t2;
    const float rz = 1.0f / tcz;

    const float limx = 1.3f * (0.5f * width / fx);
    const float limy = 1.3f * (0.5f * height / fy);
    const float txz = fminf(fmaxf(tcx * rz, -limx), limx);
    const float tyz = fminf(fmaxf(tcy * rz, -limy), limy);

    // cov_cam = W3 S W3^T
    const float V00 = W00*S00 + W01*S01 + W02*S02;
    const float V01 = W00*S01 + W01*S11 + W02*S12;
    const float V02 = W00*S02 + W01*S12 + W02*S22;
    const float V10 = W10*S00 + W11*S01 + W12*S02;
    const float V11 = W10*S01 + W11*S11 + W12*S12;
    const float V12 = W10*S02 + W11*S12 + W12*S22;
    const float V20 = W20*S00 + W21*S01 + W22*S02;
    const float V21 = W20*S01 + W21*S11 + W22*S12;
    const float V22 = W20*S02 + W21*S12 + W22*S22;
    const float CC00 = V00*W00 + V01*W01 + V02*W02;
    const float CC01 = V00*W10 + V01*W11 + V02*W12;
    const float CC02 = V00*W20 + V01*W21 + V02*W22;
    const float CC11 = V10*W10 + V11*W11 + V12*W12;
    const float CC12 = V10*W20 + V11*W21 + V12*W22;
    const float CC22 = V20*W20 + V21*W21 + V22*W22;

    // J (2x3)
    const float j00 = fx * rz,  j02 = -fx * txz * rz;
    const float j11 = fy * rz,  j12 = -fy * tyz * rz;

    // cov2d = J CC J^T
    const float u0 = j00*CC00 + j02*CC02;
    const float u1 = j00*CC01 + j02*CC12;
    const float u2 = j00*CC02 + j02*CC22;
    const float v1 = j11*CC11 + j12*CC12;
    const float v2 = j11*CC12 + j12*CC22;
    const float c2d00 = u0*j00 + u2*j02;
    const float c2d01 = u1*j11 + u2*j12;
    const float c2d11 = v1*j11 + v2*j12;

    const float a  = c2d00 + EPS2D;
    const float bb = c2d01;
    const float cc = c2d11 + EPS2D;
    const float det = a*cc - bb*bb;
    const float det_safe = (det > 0.0f) ? det : 1.0f;
    const float invd = 1.0f / det_safe;

    const bool valid = (tcz > NEAR_PLANE) && (tcz < FAR_PLANE) && (det > 0.0f);

    // conservative cull radius: alpha >= 1/255 needs sigma <= ln(255*op);
    // sigma = 0.5 d^T Sigma^-1 d >= 0.5 |d|^2 / lambda_max(Sigma)
    float rad = 0.0f;
    if (valid && op >= ALPHA_MIN) {
        const float lmax = 0.5f*(a + cc) + sqrtf(fmaxf(0.f, 0.25f*(a - cc)*(a - cc) + bb*bb));
        const float sig_cut = logf(255.0f * op);
        rad = sqrtf(fmaxf(sig_cut, 0.0f) * 2.0f * lmax) * 1.001f + 0.5f;
    }

    const float mx2d = fx * tcx * rz + cx;
    const float my2d = fy * tcy * rz + cy;

    // store HALF conic coefficients (exact power-of-two scale)
    attrs[i*3+0] = make_float4(mx2d, my2d, 0.5f * cc * invd, -bb * invd);  // mx, my, A/2, B
    attrs[i*3+1] = make_float4(0.5f * a * invd, op, tcz, rad);             // C/2, op, tz, rad
    attrs[i*3+2] = make_float4(col[0], col[1], col[2], 0.0f);             // r, g, b
    tz_arr[i] = tcz;
}

// --- kernel 2: stable rank sort (one wave/element) + scatter to sorted order
__global__ __launch_bounds__(64) void sort_scatter_kernel(
    const float* __restrict__ tz, const float4* __restrict__ attrs,
    float4* __restrict__ attrs_s, float4* __restrict__ bounds_s, int N)
{
    const int i = blockIdx.x;
    const int lane = threadIdx.x;
    const float k = tz[i];

    int rank = 0;
    int j = lane * 4;
    const int Nv = N & ~3;
    for (; j + 3 < Nv; j += 256) {
        const float4 v = *reinterpret_cast<const float4*>(tz + j);
        rank += (v.x < k) || (v.x == k && (j + 0) < i);
        rank += (v.y < k) || (v.y == k && (j + 1) < i);
        rank += (v.z < k) || (v.z == k && (j + 2) < i);
        rank += (v.w < k) || (v.w == k && (j + 3) < i);
    }
    const int t = Nv + lane;
    if (t < N) {
        const float kj = tz[t];
        rank += (kj < k) || (kj == k && t < i);
    }

    #pragma unroll
    for (int off = 32; off > 0; off >>= 1) rank += __shfl_down(rank, off);
    rank = __shfl(rank, 0);

    if (lane < 3) attrs_s[rank*3 + lane] = attrs[i*3 + lane];
    if (lane == 3) {
        const float4 g0 = attrs[i*3+0];
        const float4 g1 = attrs[i*3+1];
        bounds_s[rank] = make_float4(g0.x, g0.y, g1.w, 0.0f);   // mx, my, rad
    }
}

// ---- kernel 3: tiled rasterize, 4 waves/tile, segmented exact composite ---
// T = cumprod(1-alpha) is cutoff-independent in the reference, so segment
// transmittance products compose exactly:
//   phase 1: wave w computes P_w(pixel) = prod over its segment of (1-alpha)
//   prefix:  T_start_w = prod_{m<w} P_m   (per pixel, via LDS)
//   phase 2: composite own segment from T_start_w with exact T_EPS gating.
__device__ __forceinline__ float eval_alpha(const float4 g0, const float4 g1,
                                            const float px, const float py) {
    const float ddx = px - g0.x;
    const float ddy = py - g0.y;
    const float sg = g0.z*ddx*ddx + g1.x*ddy*ddy + g0.w*ddx*ddy;
    float a = g1.y * expf(-sg);
    return ((sg >= 0.0f) && (a >= ALPHA_MIN)) ? fminf(a, ALPHA_MAX) : 0.0f;
}

__global__ __launch_bounds__(256) void raster_kernel(
    const float4* __restrict__ attrs_s, const float4* __restrict__ bounds_s,
    float* __restrict__ out, int N, int P, const int* __restrict__ wptr)
{
    extern __shared__ int smem[];              // NW * NR ints (per-wave lists)
    __shared__ float s_P[NW][64];              // per-wave, per-pixel segment product
    __shared__ float s_red[NW][64][5];         // per-wave partial accumulators

    const int width  = wptr[0];
    const int height = P / width;
    const int tilesX = (width  + TS - 1) / TS;
    const int tilesY = (height + TS - 1) / TS;
    const int nTiles = tilesX * tilesY;
    const int lane = threadIdx.x & 63;
    const int wv   = threadIdx.x >> 6;

    const int NR = (((N + NW - 1) / NW) + 63) & ~63;   // segment span, mult of 64
    int* s_list = smem + wv * NR;
    const int rstart = wv * NR;
    const int rend   = min(rstart + NR, N);

    for (int tile = blockIdx.x; tile < nTiles; tile += gridDim.x) {
        __syncthreads();   // protect smem reuse across grid-stride iterations

        const int tx = tile % tilesX, ty = tile / tilesX;
        const float x0 = (float)(tx*TS) + 0.5f;
        const float x1 = (float)(min(tx*TS + TS - 1, width  - 1)) + 0.5f;
        const float y0 = (float)(ty*TS) + 0.5f;
        const float y1 = (float)(min(ty*TS + TS - 1, height - 1)) + 0.5f;

        // ---- per-wave cull scan over [rstart, rend): own sub-list, in order
        int count = 0;
        for (int base = rstart; base < rend; base += 64) {
            const int j = base + lane;
            bool pred = false;
            if (j < rend) {
                const float4 b = bounds_s[j];          // mx, my, rad
                pred = (b.z > 0.0f) &&
                       (b.x + b.z >= x0) && (b.x - b.z <= x1) &&
                       (b.y + b.z >= y0) && (b.y - b.z <= y1);
            }
            const unsigned long long m = __ballot(pred);
            const int pre = __popcll(m & ((1ull << lane) - 1ull));
            if (pred) s_list[count + pre] = j;          // sorted position
            count += (int)__popcll(m);
        }
        __syncthreads();

        // ---- pixel for this lane
        const int px_i = tx*TS + (lane & (TS-1));
        const int py_i = ty*TS + (lane >> 3);
        const bool active = (px_i < width) && (py_i < height);
        const float px = (float)px_i + 0.5f;
        const float py = (float)py_i + 0.5f;

        // ---- phase 1: segment transmittance product (4-wide ILP) ----------
        float Pw = 1.0f;
        for (int p = 0; p < count; p += 4) {
            const int4 s4 = *reinterpret_cast<const int4*>(&s_list[p]);
            int id[4];
            id[0] = s4.x;
            id[1] = (p+1 < count) ? s4.y : s4.x;
            id[2] = (p+2 < count) ? s4.z : s4.x;
            id[3] = (p+3 < count) ? s4.w : s4.x;
            float al[4];
            #pragma unroll
            for (int u = 0; u < 4; u++) {
                const int idx = __builtin_amdgcn_readfirstlane(id[u]);
                const float4 g0 = attrs_s[idx*3+0];
                const float4 g1 = attrs_s[idx*3+1];
                const float a = eval_alpha(g0, g1, px, py);
                al[u] = (p+u < count) ? a : 0.0f;
            }
            Pw *= (1.0f - al[0]);
            Pw *= (1.0f - al[1]);
            Pw *= (1.0f - al[2]);
            Pw *= (1.0f - al[3]);
        }
        s_P[wv][lane] = Pw;
        __syncthreads();

        // ---- per-pixel prefix transmittance for this segment --------------
        float T = active ? 1.0f : 0.0f;
        for (int m = 0; m < wv; m++) T *= s_P[m][lane];

        // ---- phase 2: composite own segment from T_start ------------------
        float accr = 0.f, accg = 0.f, accb = 0.f, accd = 0.f, acca = 0.f;
        if (!__all(T <= T_EPS)) {
            for (int p = 0; p < count; p += 4) {
                const int4 s4 = *reinterpret_cast<const int4*>(&s_list[p]);
                int id[4];
                id[0] = s4.x;
                id[1] = (p+1 < count) ? s4.y : s4.x;
                id[2] = (p+2 < count) ? s4.z : s4.x;
                id[3] = (p+3 < count) ? s4.w : s4.x;
                #pragma unroll
                for (int u = 0; u < 4; u++) {
                    const int idx = __builtin_amdgcn_readfirstlane(id[u]);
                    const float4 g0 = attrs_s[idx*3+0];
                    const float4 g1 = attrs_s[idx*3+1];
                    const float4 g2 = attrs_s[idx*3+2];
                    float a = eval_alpha(g0, g1, px, py);
                    a = (p+u < count) ? a : 0.0f;
                    const float w = (T > T_EPS) ? a * T : 0.0f;
                    accr += w * g2.x;
                    accg += w * g2.y;
                    accb += w * g2.z;
                    accd += w * g1.z;
                    acca += w;
                    T *= (1.0f - a);
                }
                if (__all(T <= T_EPS)) break;
            }
        }

        // ---- cross-wave reduction ----------------------------------------
        s_red[wv][lane][0] = accr;
        s_red[wv][lane][1] = accg;
        s_red[wv][lane][2] = accb;
        s_red[wv][lane][3] = accd;
        s_red[wv][lane][4] = acca;
        __syncthreads();

        if (wv == 0 && active) {
            float r = 0.f, g = 0.f, b = 0.f, d = 0.f, a = 0.f;
            #pragma unroll
            for (int m = 0; m < NW; m++) {
                r += s_red[m][lane][0];
                g += s_red[m][lane][1];
                b += s_red[m][lane][2];
                d += s_red[m][lane][3];
                a += s_red[m][lane][4];
            }
            const int pix = py_i * width + px_i;
            out[pix*4 + 0] = r;
            out[pix*4 + 1] = g;
            out[pix*4 + 2] = b;
            out[pix*4 + 3] = d / fmaxf(a, 1e-10f);
            out[(size_t)P*4 + pix] = a;
        }
    }
}

// ---------------- host-side launch ----------------
extern "C" void kernel_launch(void* const* d_in, const int* in_sizes, int n_in,
                              void* d_out, int out_size, void* d_ws, size_t ws_size,
                              hipStream_t stream) {
    const float* means   = (const float*)d_in[0];
    const float* opac    = (const float*)d_in[1];
    const float* scales  = (const float*)d_in[2];
    const float* quats   = (const float*)d_in[3];
    const float* sh0     = (const float*)d_in[4];
    const float* shN     = (const float*)d_in[5];
    const float* c2w     = (const float*)d_in[6];
    const float* Ks      = (const float*)d_in[7];
    const int*   wptr    = (const int*)d_in[8];
    const int*   hptr    = (const int*)d_in[9];

    const int N = in_sizes[0] / 3;
    const int P = out_size / 5;

    float4* attrs    = (float4*)d_ws;                  // 3*N float4
    float4* attrs_s  = attrs + 3*N;                    // 3*N float4 (sorted)
    float4* bounds_s = attrs_s + 3*N;                  // N float4 (sorted mx,my,rad)
    float*  tz_u     = (float*)(bounds_s + N);         // N floats

    const int gb = (N + 255) / 256;
    hipLaunchKernelGGL(preprocess_kernel, dim3(gb), dim3(256), 0, stream,
                       means, opac, scales, quats, sh0, shN, c2w, Ks, wptr, hptr,
                       attrs, tz_u, N);

    hipLaunchKernelGGL(sort_scatter_kernel, dim3(N), dim3(64), 0, stream,
                       tz_u, attrs, attrs_s, bounds_s, N);

    const int NR = (((N + NW - 1) / NW) + 63) & ~63;
    const size_t lds = (size_t)NW * NR * sizeof(int);
    hipLaunchKernelGGL(raster_kernel, dim3(512), dim3(256), lds, stream,
                       attrs_s, bounds_s, (float*)d_out, N, P, wptr);
}

// Round 7
// 24.434 us; speedup vs baseline: 26.6719x; 1.0964x over previous
//
#include <hip/hip_runtime.h>
#include <math.h>

#define SH_C0f 0.28209479177387814f
#define SH_C1f 0.4886025119029199f
#define EPS2D 0.3f
#define NEAR_PLANE 0.01f
#define FAR_PLANE 1e10f
#define ALPHA_MIN (1.0f/255.0f)
#define ALPHA_MAX 0.999f
#define T_EPS 1e-4f
#define TS 8   // tile size (8x8 pixels)
#define NW 8   // waves per raster block (list segments)

// ---------------- kernel 1: per-gaussian preprocess (inline 4x4 inverse) ---
__global__ void preprocess_kernel(
    const float* __restrict__ means, const float* __restrict__ opac_in,
    const float* __restrict__ scales, const float* __restrict__ quats,
    const float* __restrict__ sh0, const float* __restrict__ shN,
    const float* __restrict__ c2w, const float* __restrict__ Ks,
    const int* __restrict__ wptr, const int* __restrict__ hptr,
    float4* __restrict__ attrs, float* __restrict__ tz_arr, int N)
{
    int i = blockIdx.x * blockDim.x + threadIdx.x;
    if (i >= N) return;

    // ---- inline general 4x4 inverse of camtoworlds (rows 0..2 needed) ----
    float m[16];
    #pragma unroll
    for (int k = 0; k < 16; k++) m[k] = c2w[k];
    float inv[12];
    inv[0]  =  m[5]*m[10]*m[15] - m[5]*m[11]*m[14] - m[9]*m[6]*m[15] + m[9]*m[7]*m[14] + m[13]*m[6]*m[11] - m[13]*m[7]*m[10];
    inv[4]  = -m[4]*m[10]*m[15] + m[4]*m[11]*m[14] + m[8]*m[6]*m[15] - m[8]*m[7]*m[14] - m[12]*m[6]*m[11] + m[12]*m[7]*m[10];
    inv[8]  =  m[4]*m[9]*m[15]  - m[4]*m[11]*m[13] - m[8]*m[5]*m[15] + m[8]*m[7]*m[13] + m[12]*m[5]*m[11] - m[12]*m[7]*m[9];
    inv[1]  = -m[1]*m[10]*m[15] + m[1]*m[11]*m[14] + m[9]*m[2]*m[15] - m[9]*m[3]*m[14] - m[13]*m[2]*m[11] + m[13]*m[3]*m[10];
    inv[5]  =  m[0]*m[10]*m[15] - m[0]*m[11]*m[14] - m[8]*m[2]*m[15] + m[8]*m[3]*m[14] + m[12]*m[2]*m[11] - m[12]*m[3]*m[10];
    inv[9]  = -m[0]*m[9]*m[15]  + m[0]*m[11]*m[13] + m[8]*m[1]*m[15] - m[8]*m[3]*m[13] - m[12]*m[1]*m[11] + m[12]*m[3]*m[9];
    inv[2]  =  m[1]*m[6]*m[15]  - m[1]*m[7]*m[14]  - m[5]*m[2]*m[15] + m[5]*m[3]*m[14] + m[13]*m[2]*m[7]  - m[13]*m[3]*m[6];
    inv[6]  = -m[0]*m[6]*m[15]  + m[0]*m[7]*m[14]  + m[4]*m[2]*m[15] - m[4]*m[3]*m[14] - m[12]*m[2]*m[7]  + m[12]*m[3]*m[6];
    inv[10] =  m[0]*m[5]*m[15]  - m[0]*m[7]*m[13]  - m[4]*m[1]*m[15] + m[4]*m[3]*m[13] + m[12]*m[1]*m[7]  - m[12]*m[3]*m[5];
    inv[3]  = -m[1]*m[6]*m[11]  + m[1]*m[7]*m[10]  + m[5]*m[2]*m[11] - m[5]*m[3]*m[10] - m[9]*m[2]*m[7]   + m[9]*m[3]*m[6];
    inv[7]  =  m[0]*m[6]*m[11]  - m[0]*m[7]*m[10]  - m[4]*m[2]*m[11] + m[4]*m[3]*m[10] + m[8]*m[2]*m[7]   - m[8]*m[3]*m[6];
    inv[11] = -m[0]*m[5]*m[11]  + m[0]*m[7]*m[9]   + m[4]*m[1]*m[11] - m[4]*m[3]*m[9]  - m[8]*m[1]*m[7]   + m[8]*m[3]*m[5];
    {
        float inv12 = -m[4]*m[9]*m[14] + m[4]*m[10]*m[13] + m[8]*m[5]*m[14] - m[8]*m[6]*m[13] - m[12]*m[5]*m[10] + m[12]*m[6]*m[9];
        float det = m[0]*inv[0] + m[1]*inv[4] + m[2]*inv[8] + m[3]*inv12;
        float r = 1.0f / det;
        #pragma unroll
        for (int k = 0; k < 12; k++) inv[k] *= r;
    }
    const float W00 = inv[0], W01 = inv[1], W02 = inv[2],  t0 = inv[3];
    const float W10 = inv[4], W11 = inv[5], W12 = inv[6],  t1 = inv[7];
    const float W20 = inv[8], W21 = inv[9], W22 = inv[10], t2 = inv[11];

    const float fx = Ks[0], cx = Ks[2], fy = Ks[4], cy = Ks[5];
    const float width = (float)wptr[0], height = (float)hptr[0];

    const float mxx = means[i*3+0], myy = means[i*3+1], mzz = means[i*3+2];

    // view direction from camera position (camtoworlds[0,:3,3])
    const float cpx = m[3], cpy = m[7], cpz = m[11];
    float dx = mxx - cpx, dy = myy - cpy, dz = mzz - cpz;
    float dn = sqrtf(dx*dx + dy*dy + dz*dz);
    dx /= dn; dy /= dn; dz /= dn;

    // SH degree-1 color
    float col[3];
    #pragma unroll
    for (int c = 0; c < 3; c++) {
        float v = SH_C0f * sh0[i*3+c]
                + SH_C1f * (-dy * shN[i*9 + 0*3 + c] + dz * shN[i*9 + 1*3 + c] - dx * shN[i*9 + 2*3 + c])
                + 0.5f;
        col[c] = fmaxf(v, 0.0f);
    }

    // sigmoid opacity
    const float op = 1.0f / (1.0f + expf(-opac_in[i]));

    // quat -> R (normalized)
    float qw = quats[i*4+0], qx = quats[i*4+1], qy = quats[i*4+2], qz = quats[i*4+3];
    float qn = sqrtf(qw*qw + qx*qx + qy*qy + qz*qz);
    qw /= qn; qx /= qn; qy /= qn; qz /= qn;
    const float R00 = 1.f - 2.f*(qy*qy + qz*qz), R01 = 2.f*(qx*qy - qw*qz), R02 = 2.f*(qx*qz + qw*qy);
    const float R10 = 2.f*(qx*qy + qw*qz), R11 = 1.f - 2.f*(qx*qx + qz*qz), R12 = 2.f*(qy*qz - qw*qx);
    const float R20 = 2.f*(qx*qz - qw*qy), R21 = 2.f*(qy*qz + qw*qx), R22 = 1.f - 2.f*(qx*qx + qy*qy);

    const float sx = scales[i*3+0], sy = scales[i*3+1], sz = scales[i*3+2];
    const float M00 = R00*sx, M01 = R01*sy, M02 = R02*sz;
    const float M10 = R10*sx, M11 = R11*sy, M12 = R12*sz;
    const float M20 = R20*sx, M21 = R21*sy, M22 = R22*sz;

    // cov3d = M M^T (symmetric)
    const float S00 = M00*M00 + M01*M01 + M02*M02;
    const float S01 = M00*M10 + M01*M11 + M02*M12;
    const float S02 = M00*M20 + M01*M21 + M02*M22;
    const float S11 = M10*M10 + M11*M11 + M12*M12;
    const float S12 = M10*M20 + M11*M21 + M12*M22;
    const float S22 = M20*M20 + M21*M21 + M22*M22;

    // camera-space mean
    const float tcx = W00*mxx + W01*myy + W02*mzz + t0;
    const float tcy = W10*mxx + W11*myy + W12*mzz + t1;
    const float tcz = W20*mxx + W21*myy + W22*mzz + t2;
    const float rz = 1.0f / tcz;

    const float limx = 1.3f * (0.5f * width / fx);
    const float limy = 1.3f * (0.5f * height / fy);
    const float txz = fminf(fmaxf(tcx * rz, -limx), limx);
    const float tyz = fminf(fmaxf(tcy * rz, -limy), limy);

    // cov_cam = W3 S W3^T
    const float V00 = W00*S00 + W01*S01 + W02*S02;
    const float V01 = W00*S01 + W01*S11 + W02*S12;
    const float V02 = W00*S02 + W01*S12 + W02*S22;
    const float V10 = W10*S00 + W11*S01 + W12*S02;
    const float V11 = W10*S01 + W11*S11 + W12*S12;
    const float V12 = W10*S02 + W11*S12 + W12*S22;
    const float V20 = W20*S00 + W21*S01 + W22*S02;
    const float V21 = W20*S01 + W21*S11 + W22*S12;
    const float V22 = W20*S02 + W21*S12 + W22*S22;
    const float CC00 = V00*W00 + V01*W01 + V02*W02;
    const float CC01 = V00*W10 + V01*W11 + V02*W12;
    const float CC02 = V00*W20 + V01*W21 + V02*W22;
    const float CC11 = V10*W10 + V11*W11 + V12*W12;
    const float CC12 = V10*W20 + V11*W21 + V12*W22;
    const float CC22 = V20*W20 + V21*W21 + V22*W22;

    // J (2x3)
    const float j00 = fx * rz,  j02 = -fx * txz * rz;
    const float j11 = fy * rz,  j12 = -fy * tyz * rz;

    // cov2d = J CC J^T
    const float u0 = j00*CC00 + j02*CC02;
    const float u1 = j00*CC01 + j02*CC12;
    const float u2 = j00*CC02 + j02*CC22;
    const float v1 = j11*CC11 + j12*CC12;
    const float v2 = j11*CC12 + j12*CC22;
    const float c2d00 = u0*j00 + u2*j02;
    const float c2d01 = u1*j11 + u2*j12;
    const float c2d11 = v1*j11 + v2*j12;

    const float a  = c2d00 + EPS2D;
    const float bb = c2d01;
    const float cc = c2d11 + EPS2D;
    const float det = a*cc - bb*bb;
    const float det_safe = (det > 0.0f) ? det : 1.0f;
    const float invd = 1.0f / det_safe;

    const bool valid = (tcz > NEAR_PLANE) && (tcz < FAR_PLANE) && (det > 0.0f);

    // conservative cull radius: alpha >= 1/255 needs sigma <= ln(255*op);
    // sigma = 0.5 d^T Sigma^-1 d >= 0.5 |d|^2 / lambda_max(Sigma)
    float rad = 0.0f;
    if (valid && op >= ALPHA_MIN) {
        const float lmax = 0.5f*(a + cc) + sqrtf(fmaxf(0.f, 0.25f*(a - cc)*(a - cc) + bb*bb));
        const float sig_cut = logf(255.0f * op);
        rad = sqrtf(fmaxf(sig_cut, 0.0f) * 2.0f * lmax) * 1.001f + 0.5f;
    }

    const float mx2d = fx * tcx * rz + cx;
    const float my2d = fy * tcy * rz + cy;

    // store HALF conic coefficients (exact power-of-two scale)
    attrs[i*3+0] = make_float4(mx2d, my2d, 0.5f * cc * invd, -bb * invd);  // mx, my, A/2, B
    attrs[i*3+1] = make_float4(0.5f * a * invd, op, tcz, rad);             // C/2, op, tz, rad
    attrs[i*3+2] = make_float4(col[0], col[1], col[2], 0.0f);             // r, g, b
    tz_arr[i] = tcz;
}

// --- kernel 2: stable rank sort (one wave/element) + scatter to sorted order
__global__ __launch_bounds__(64) void sort_scatter_kernel(
    const float* __restrict__ tz, const float4* __restrict__ attrs,
    float4* __restrict__ attrs_s, float4* __restrict__ bounds_s, int N)
{
    const int i = blockIdx.x;
    const int lane = threadIdx.x;
    const float k = tz[i];

    int rank = 0;
    int j = lane * 4;
    const int Nv = N & ~3;
    for (; j + 3 < Nv; j += 256) {
        const float4 v = *reinterpret_cast<const float4*>(tz + j);
        rank += (v.x < k) || (v.x == k && (j + 0) < i);
        rank += (v.y < k) || (v.y == k && (j + 1) < i);
        rank += (v.z < k) || (v.z == k && (j + 2) < i);
        rank += (v.w < k) || (v.w == k && (j + 3) < i);
    }
    const int t = Nv + lane;
    if (t < N) {
        const float kj = tz[t];
        rank += (kj < k) || (kj == k && t < i);
    }

    #pragma unroll
    for (int off = 32; off > 0; off >>= 1) rank += __shfl_down(rank, off);
    rank = __shfl(rank, 0);

    if (lane < 3) attrs_s[rank*3 + lane] = attrs[i*3 + lane];
    if (lane == 3) {
        const float4 g0 = attrs[i*3+0];
        const float4 g1 = attrs[i*3+1];
        bounds_s[rank] = make_float4(g0.x, g0.y, g1.w, 0.0f);   // mx, my, rad
    }
}

// ---- kernel 3: tiled rasterize, NW waves/tile, segmented exact composite --
// T = cumprod(1-alpha) is cutoff-independent in the reference, so segment
// transmittance products compose exactly:
//   phase 1: wave w computes P_w(pixel) = prod over its segment of (1-alpha)
//            (last wave skips it: nobody consumes P_{NW-1}; early-out when
//             __all(partial <= T_EPS): all downstream weights are gated by
//             T > T_EPS, so the exact sub-threshold value is output-neutral)
//   prefix:  T_start_w = prod_{m<w} P_m   (per pixel, via LDS)
//   phase 2: composite own segment from T_start_w with exact T_EPS gating.
__device__ __forceinline__ float eval_alpha(const float4 g0, const float4 g1,
                                            const float px, const float py) {
    const float ddx = px - g0.x;
    const float ddy = py - g0.y;
    const float sg = g0.z*ddx*ddx + g1.x*ddy*ddy + g0.w*ddx*ddy;
    float a = g1.y * expf(-sg);
    return ((sg >= 0.0f) && (a >= ALPHA_MIN)) ? fminf(a, ALPHA_MAX) : 0.0f;
}

__global__ __launch_bounds__(512) void raster_kernel(
    const float4* __restrict__ attrs_s, const float4* __restrict__ bounds_s,
    float* __restrict__ out, int N, int P, const int* __restrict__ wptr)
{
    extern __shared__ int smem[];              // NW * NR ints (per-wave lists)
    __shared__ float s_P[NW][64];              // per-wave, per-pixel segment product
    __shared__ float s_red[NW][64][5];         // per-wave partial accumulators

    const int width  = wptr[0];
    const int height = P / width;
    const int tilesX = (width  + TS - 1) / TS;
    const int tilesY = (height + TS - 1) / TS;
    const int nTiles = tilesX * tilesY;
    const int lane = threadIdx.x & 63;
    const int wv   = threadIdx.x >> 6;

    const int NR = (((N + NW - 1) / NW) + 63) & ~63;   // segment span, mult of 64
    int* s_list = smem + wv * NR;
    const int rstart = wv * NR;
    const int rend   = min(rstart + NR, N);

    for (int tile = blockIdx.x; tile < nTiles; tile += gridDim.x) {
        __syncthreads();   // protect smem reuse across grid-stride iterations

        const int tx = tile % tilesX, ty = tile / tilesX;
        const float x0 = (float)(tx*TS) + 0.5f;
        const float x1 = (float)(min(tx*TS + TS - 1, width  - 1)) + 0.5f;
        const float y0 = (float)(ty*TS) + 0.5f;
        const float y1 = (float)(min(ty*TS + TS - 1, height - 1)) + 0.5f;

        // ---- per-wave cull scan over [rstart, rend): own sub-list, in order
        int count = 0;
        for (int base = rstart; base < rend; base += 64) {
            const int j = base + lane;
            bool pred = false;
            if (j < rend) {
                const float4 b = bounds_s[j];          // mx, my, rad
                pred = (b.z > 0.0f) &&
                       (b.x + b.z >= x0) && (b.x - b.z <= x1) &&
                       (b.y + b.z >= y0) && (b.y - b.z <= y1);
            }
            const unsigned long long m = __ballot(pred);
            const int pre = __popcll(m & ((1ull << lane) - 1ull));
            if (pred) s_list[count + pre] = j;          // sorted position
            count += (int)__popcll(m);
        }
        __syncthreads();

        // ---- pixel for this lane
        const int px_i = tx*TS + (lane & (TS-1));
        const int py_i = ty*TS + (lane >> 3);
        const bool active = (px_i < width) && (py_i < height);
        const float px = (float)px_i + 0.5f;
        const float py = (float)py_i + 0.5f;

        // ---- phase 1: segment transmittance product (4-wide ILP) ----------
        if (wv < NW-1) {                       // last wave's product is unused
            float Pw = 1.0f;
            for (int p = 0; p < count; p += 4) {
                const int4 s4 = *reinterpret_cast<const int4*>(&s_list[p]);
                int id[4];
                id[0] = s4.x;
                id[1] = (p+1 < count) ? s4.y : s4.x;
                id[2] = (p+2 < count) ? s4.z : s4.x;
                id[3] = (p+3 < count) ? s4.w : s4.x;
                float al[4];
                #pragma unroll
                for (int u = 0; u < 4; u++) {
                    const int idx = __builtin_amdgcn_readfirstlane(id[u]);
                    const float4 g0 = attrs_s[idx*3+0];
                    const float4 g1 = attrs_s[idx*3+1];
                    const float a = eval_alpha(g0, g1, px, py);
                    al[u] = (p+u < count) ? a : 0.0f;
                }
                Pw *= (1.0f - al[0]);
                Pw *= (1.0f - al[1]);
                Pw *= (1.0f - al[2]);
                Pw *= (1.0f - al[3]);
                if (__all(Pw <= T_EPS)) break;   // output-exact: see header note
            }
            s_P[wv][lane] = Pw;
        }
        __syncthreads();

        // ---- per-pixel prefix transmittance for this segment --------------
        float T = active ? 1.0f : 0.0f;
        for (int m = 0; m < wv; m++) T *= s_P[m][lane];

        // ---- phase 2: composite own segment from T_start ------------------
        float accr = 0.f, accg = 0.f, accb = 0.f, accd = 0.f, acca = 0.f;
        if (!__all(T <= T_EPS)) {
            for (int p = 0; p < count; p += 4) {
                const int4 s4 = *reinterpret_cast<const int4*>(&s_list[p]);
                int id[4];
                id[0] = s4.x;
                id[1] = (p+1 < count) ? s4.y : s4.x;
                id[2] = (p+2 < count) ? s4.z : s4.x;
                id[3] = (p+3 < count) ? s4.w : s4.x;
                #pragma unroll
                for (int u = 0; u < 4; u++) {
                    const int idx = __builtin_amdgcn_readfirstlane(id[u]);
                    const float4 g0 = attrs_s[idx*3+0];
                    const float4 g1 = attrs_s[idx*3+1];
                    const float4 g2 = attrs_s[idx*3+2];
                    float a = eval_alpha(g0, g1, px, py);
                    a = (p+u < count) ? a : 0.0f;
                    const float w = (T > T_EPS) ? a * T : 0.0f;
                    accr += w * g2.x;
                    accg += w * g2.y;
                    accb += w * g2.z;
                    accd += w * g1.z;
                    acca += w;
                    T *= (1.0f - a);
                }
                if (__all(T <= T_EPS)) break;
            }
        }

        // ---- cross-wave reduction ----------------------------------------
        s_red[wv][lane][0] = accr;
        s_red[wv][lane][1] = accg;
        s_red[wv][lane][2] = accb;
        s_red[wv][lane][3] = accd;
        s_red[wv][lane][4] = acca;
        __syncthreads();

        if (wv == 0 && active) {
            float r = 0.f, g = 0.f, b = 0.f, d = 0.f, a = 0.f;
            #pragma unroll
            for (int m = 0; m < NW; m++) {
                r += s_red[m][lane][0];
                g += s_red[m][lane][1];
                b += s_red[m][lane][2];
                d += s_red[m][lane][3];
                a += s_red[m][lane][4];
            }
            const int pix = py_i * width + px_i;
            out[pix*4 + 0] = r;
            out[pix*4 + 1] = g;
            out[pix*4 + 2] = b;
            out[pix*4 + 3] = d / fmaxf(a, 1e-10f);
            out[(size_t)P*4 + pix] = a;
        }
    }
}

// ---------------- host-side launch ----------------
extern "C" void kernel_launch(void* const* d_in, const int* in_sizes, int n_in,
                              void* d_out, int out_size, void* d_ws, size_t ws_size,
                              hipStream_t stream) {
    const float* means   = (const float*)d_in[0];
    const float* opac    = (const float*)d_in[1];
    const float* scales  = (const float*)d_in[2];
    const float* quats   = (const float*)d_in[3];
    const float* sh0     = (const float*)d_in[4];
    const float* shN     = (const float*)d_in[5];
    const float* c2w     = (const float*)d_in[6];
    const float* Ks      = (const float*)d_in[7];
    const int*   wptr    = (const int*)d_in[8];
    const int*   hptr    = (const int*)d_in[9];

    const int N = in_sizes[0] / 3;
    const int P = out_size / 5;

    float4* attrs    = (float4*)d_ws;                  // 3*N float4
    float4* attrs_s  = attrs + 3*N;                    // 3*N float4 (sorted)
    float4* bounds_s = attrs_s + 3*N;                  // N float4 (sorted mx,my,rad)
    float*  tz_u     = (float*)(bounds_s + N);         // N floats

    const int gb = (N + 255) / 256;
    hipLaunchKernelGGL(preprocess_kernel, dim3(gb), dim3(256), 0, stream,
                       means, opac, scales, quats, sh0, shN, c2w, Ks, wptr, hptr,
                       attrs, tz_u, N);

    hipLaunchKernelGGL(sort_scatter_kernel, dim3(N), dim3(64), 0, stream,
                       tz_u, attrs, attrs_s, bounds_s, N);

    const int NR = (((N + NW - 1) / NW) + 63) & ~63;
    const size_t lds = (size_t)NW * NR * sizeof(int);
    hipLaunchKernelGGL(raster_kernel, dim3(512), dim3(512), lds, stream,
                       attrs_s, bounds_s, (float*)d_out, N, P, wptr);
}

// Round 8
// 21.579 us; speedup vs baseline: 30.1998x; 1.1323x over previous
//
#include <hip/hip_runtime.h>
#include <math.h>

#define SH_C0f 0.28209479177387814f
#define SH_C1f 0.4886025119029199f
#define EPS2D 0.3f
#define NEAR_PLANE 0.01f
#define FAR_PLANE 1e10f
#define ALPHA_MIN (1.0f/255.0f)
#define ALPHA_MAX 0.999f
#define T_EPS 1e-4f
#define TS 8   // tile size (8x8 pixels)
#define NW 8   // waves per raster block (list segments)

// ---------------- kernel 1: per-gaussian preprocess (inline 4x4 inverse) ---
__global__ void preprocess_kernel(
    const float* __restrict__ means, const float* __restrict__ opac_in,
    const float* __restrict__ scales, const float* __restrict__ quats,
    const float* __restrict__ sh0, const float* __restrict__ shN,
    const float* __restrict__ c2w, const float* __restrict__ Ks,
    const int* __restrict__ wptr, const int* __restrict__ hptr,
    float4* __restrict__ attrs, float* __restrict__ tz_arr, int N)
{
    int i = blockIdx.x * blockDim.x + threadIdx.x;
    if (i >= N) return;

    // ---- inline general 4x4 inverse of camtoworlds (rows 0..2 needed) ----
    float m[16];
    #pragma unroll
    for (int k = 0; k < 16; k++) m[k] = c2w[k];
    float inv[12];
    inv[0]  =  m[5]*m[10]*m[15] - m[5]*m[11]*m[14] - m[9]*m[6]*m[15] + m[9]*m[7]*m[14] + m[13]*m[6]*m[11] - m[13]*m[7]*m[10];
    inv[4]  = -m[4]*m[10]*m[15] + m[4]*m[11]*m[14] + m[8]*m[6]*m[15] - m[8]*m[7]*m[14] - m[12]*m[6]*m[11] + m[12]*m[7]*m[10];
    inv[8]  =  m[4]*m[9]*m[15]  - m[4]*m[11]*m[13] - m[8]*m[5]*m[15] + m[8]*m[7]*m[13] + m[12]*m[5]*m[11] - m[12]*m[7]*m[9];
    inv[1]  = -m[1]*m[10]*m[15] + m[1]*m[11]*m[14] + m[9]*m[2]*m[15] - m[9]*m[3]*m[14] - m[13]*m[2]*m[11] + m[13]*m[3]*m[10];
    inv[5]  =  m[0]*m[10]*m[15] - m[0]*m[11]*m[14] - m[8]*m[2]*m[15] + m[8]*m[3]*m[14] + m[12]*m[2]*m[11] - m[12]*m[3]*m[10];
    inv[9]  = -m[0]*m[9]*m[15]  + m[0]*m[11]*m[13] + m[8]*m[1]*m[15] - m[8]*m[3]*m[13] - m[12]*m[1]*m[11] + m[12]*m[3]*m[9];
    inv[2]  =  m[1]*m[6]*m[15]  - m[1]*m[7]*m[14]  - m[5]*m[2]*m[15] + m[5]*m[3]*m[14] + m[13]*m[2]*m[7]  - m[13]*m[3]*m[6];
    inv[6]  = -m[0]*m[6]*m[15]  + m[0]*m[7]*m[14]  + m[4]*m[2]*m[15] - m[4]*m[3]*m[14] - m[12]*m[2]*m[7]  + m[12]*m[3]*m[6];
    inv[10] =  m[0]*m[5]*m[15]  - m[0]*m[7]*m[13]  - m[4]*m[1]*m[15] + m[4]*m[3]*m[13] + m[12]*m[1]*m[7]  - m[12]*m[3]*m[5];
    inv[3]  = -m[1]*m[6]*m[11]  + m[1]*m[7]*m[10]  + m[5]*m[2]*m[11] - m[5]*m[3]*m[10] - m[9]*m[2]*m[7]   + m[9]*m[3]*m[6];
    inv[7]  =  m[0]*m[6]*m[11]  - m[0]*m[7]*m[10]  - m[4]*m[2]*m[11] + m[4]*m[3]*m[10] + m[8]*m[2]*m[7]   - m[8]*m[3]*m[6];
    inv[11] = -m[0]*m[5]*m[11]  + m[0]*m[7]*m[9]   + m[4]*m[1]*m[11] - m[4]*m[3]*m[9]  - m[8]*m[1]*m[7]   + m[8]*m[3]*m[5];
    {
        float inv12 = -m[4]*m[9]*m[14] + m[4]*m[10]*m[13] + m[8]*m[5]*m[14] - m[8]*m[6]*m[13] - m[12]*m[5]*m[10] + m[12]*m[6]*m[9];
        float det = m[0]*inv[0] + m[1]*inv[4] + m[2]*inv[8] + m[3]*inv12;
        float r = 1.0f / det;
        #pragma unroll
        for (int k = 0; k < 12; k++) inv[k] *= r;
    }
    const float W00 = inv[0], W01 = inv[1], W02 = inv[2],  t0 = inv[3];
    const float W10 = inv[4], W11 = inv[5], W12 = inv[6],  t1 = inv[7];
    const float W20 = inv[8], W21 = inv[9], W22 = inv[10], t2 = inv[11];

    const float fx = Ks[0], cx = Ks[2], fy = Ks[4], cy = Ks[5];
    const float width = (float)wptr[0], height = (float)hptr[0];

    const float mxx = means[i*3+0], myy = means[i*3+1], mzz = means[i*3+2];

    // view direction from camera position (camtoworlds[0,:3,3])
    const float cpx = m[3], cpy = m[7], cpz = m[11];
    float dx = mxx - cpx, dy = myy - cpy, dz = mzz - cpz;
    float dn = sqrtf(dx*dx + dy*dy + dz*dz);
    dx /= dn; dy /= dn; dz /= dn;

    // SH degree-1 color
    float col[3];
    #pragma unroll
    for (int c = 0; c < 3; c++) {
        float v = SH_C0f * sh0[i*3+c]
                + SH_C1f * (-dy * shN[i*9 + 0*3 + c] + dz * shN[i*9 + 1*3 + c] - dx * shN[i*9 + 2*3 + c])
                + 0.5f;
        col[c] = fmaxf(v, 0.0f);
    }

    // sigmoid opacity
    const float op = 1.0f / (1.0f + expf(-opac_in[i]));

    // quat -> R (normalized)
    float qw = quats[i*4+0], qx = quats[i*4+1], qy = quats[i*4+2], qz = quats[i*4+3];
    float qn = sqrtf(qw*qw + qx*qx + qy*qy + qz*qz);
    qw /= qn; qx /= qn; qy /= qn; qz /= qn;
    const float R00 = 1.f - 2.f*(qy*qy + qz*qz), R01 = 2.f*(qx*qy - qw*qz), R02 = 2.f*(qx*qz + qw*qy);
    const float R10 = 2.f*(qx*qy + qw*qz), R11 = 1.f - 2.f*(qx*qx + qz*qz), R12 = 2.f*(qy*qz - qw*qx);
    const float R20 = 2.f*(qx*qz - qw*qy), R21 = 2.f*(qy*qz + qw*qx), R22 = 1.f - 2.f*(qx*qx + qy*qy);

    const float sx = scales[i*3+0], sy = scales[i*3+1], sz = scales[i*3+2];
    const float M00 = R00*sx, M01 = R01*sy, M02 = R02*sz;
    const float M10 = R10*sx, M11 = R11*sy, M12 = R12*sz;
    const float M20 = R20*sx, M21 = R21*sy, M22 = R22*sz;

    // cov3d = M M^T (symmetric)
    const float S00 = M00*M00 + M01*M01 + M02*M02;
    const float S01 = M00*M10 + M01*M11 + M02*M12;
    const float S02 = M00*M20 + M01*M21 + M02*M22;
    const float S11 = M10*M10 + M11*M11 + M12*M12;
    const float S12 = M10*M20 + M11*M21 + M12*M22;
    const float S22 = M20*M20 + M21*M21 + M22*M22;

    // camera-space mean
    const float tcx = W00*mxx + W01*myy + W02*mzz + t0;
    const float tcy = W10*mxx + W11*myy + W12*mzz + t1;
    const float tcz = W20*mxx + W21*myy + W22*mzz + t2;
    const float rz = 1.0f / tcz;

    const float limx = 1.3f * (0.5f * width / fx);
    const float limy = 1.3f * (0.5f * height / fy);
    const float txz = fminf(fmaxf(tcx * rz, -limx), limx);
    const float tyz = fminf(fmaxf(tcy * rz, -limy), limy);

    // cov_cam = W3 S W3^T
    const float V00 = W00*S00 + W01*S01 + W02*S02;
    const float V01 = W00*S01 + W01*S11 + W02*S12;
    const float V02 = W00*S02 + W01*S12 + W02*S22;
    const float V10 = W10*S00 + W11*S01 + W12*S02;
    const float V11 = W10*S01 + W11*S11 + W12*S12;
    const float V12 = W10*S02 + W11*S12 + W12*S22;
    const float V20 = W20*S00 + W21*S01 + W22*S02;
    const float V21 = W20*S01 + W21*S11 + W22*S12;
    const float V22 = W20*S02 + W21*S12 + W22*S22;
    const float CC00 = V00*W00 + V01*W01 + V02*W02;
    const float CC01 = V00*W10 + V01*W11 + V02*W12;
    const float CC02 = V00*W20 + V01*W21 + V02*W22;
    const float CC11 = V10*W10 + V11*W11 + V12*W12;
    const float CC12 = V10*W20 + V11*W21 + V12*W22;
    const float CC22 = V20*W20 + V21*W21 + V22*W22;

    // J (2x3)
    const float j00 = fx * rz,  j02 = -fx * txz * rz;
    const float j11 = fy * rz,  j12 = -fy * tyz * rz;

    // cov2d = J CC J^T
    const float u0 = j00*CC00 + j02*CC02;
    const float u1 = j00*CC01 + j02*CC12;
    const float u2 = j00*CC02 + j02*CC22;
    const float v1 = j11*CC11 + j12*CC12;
    const float v2 = j11*CC12 + j12*CC22;
    const float c2d00 = u0*j00 + u2*j02;
    const float c2d01 = u1*j11 + u2*j12;
    const float c2d11 = v1*j11 + v2*j12;

    const float a  = c2d00 + EPS2D;
    const float bb = c2d01;
    const float cc = c2d11 + EPS2D;
    const float det = a*cc - bb*bb;
    const float det_safe = (det > 0.0f) ? det : 1.0f;
    const float invd = 1.0f / det_safe;

    const bool valid = (tcz > NEAR_PLANE) && (tcz < FAR_PLANE) && (det > 0.0f);

    // conservative cull radius: alpha >= 1/255 needs sigma <= ln(255*op);
    // sigma = 0.5 d^T Sigma^-1 d >= 0.5 |d|^2 / lambda_max(Sigma)
    float rad = 0.0f;
    if (valid && op >= ALPHA_MIN) {
        const float lmax = 0.5f*(a + cc) + sqrtf(fmaxf(0.f, 0.25f*(a - cc)*(a - cc) + bb*bb));
        const float sig_cut = logf(255.0f * op);
        rad = sqrtf(fmaxf(sig_cut, 0.0f) * 2.0f * lmax) * 1.001f + 0.5f;
    }

    const float mx2d = fx * tcx * rz + cx;
    const float my2d = fy * tcy * rz + cy;

    // store HALF conic coefficients (exact power-of-two scale)
    attrs[i*3+0] = make_float4(mx2d, my2d, 0.5f * cc * invd, -bb * invd);  // mx, my, A/2, B
    attrs[i*3+1] = make_float4(0.5f * a * invd, op, tcz, rad);             // C/2, op, tz, rad
    attrs[i*3+2] = make_float4(col[0], col[1], col[2], 0.0f);             // r, g, b
    tz_arr[i] = tcz;
}

// --- kernel 2: stable rank sort (one wave/element) + scatter to sorted order
__global__ __launch_bounds__(64) void sort_scatter_kernel(
    const float* __restrict__ tz, const float4* __restrict__ attrs,
    float4* __restrict__ attrs_s, float4* __restrict__ bounds_s, int N)
{
    const int i = blockIdx.x;
    const int lane = threadIdx.x;
    const float k = tz[i];

    int rank = 0;
    int j = lane * 4;
    const int Nv = N & ~3;
    for (; j + 3 < Nv; j += 256) {
        const float4 v = *reinterpret_cast<const float4*>(tz + j);
        rank += (v.x < k) || (v.x == k && (j + 0) < i);
        rank += (v.y < k) || (v.y == k && (j + 1) < i);
        rank += (v.z < k) || (v.z == k && (j + 2) < i);
        rank += (v.w < k) || (v.w == k && (j + 3) < i);
    }
    const int t = Nv + lane;
    if (t < N) {
        const float kj = tz[t];
        rank += (kj < k) || (kj == k && t < i);
    }

    #pragma unroll
    for (int off = 32; off > 0; off >>= 1) rank += __shfl_down(rank, off);
    rank = __shfl(rank, 0);

    if (lane < 3) attrs_s[rank*3 + lane] = attrs[i*3 + lane];
    if (lane == 3) {
        const float4 g0 = attrs[i*3+0];
        const float4 g1 = attrs[i*3+1];
        bounds_s[rank] = make_float4(g0.x, g0.y, g1.w, 0.0f);   // mx, my, rad
    }
}

// ---- kernel 3: tiled rasterize, NW waves/tile, single-pass scaled composite
// Wave w composites its depth-segment with LOCAL transmittance T_l (init 1,
// ungated), producing acc_w and P_w = final T_l. Then acc_w is scaled by
// T_start_w = prod_{m<w} P_m. Exact up to the reference's T_EPS cutoff:
// dropped/included tail terms telescope to <= T_EPS = 1e-4 absolute (vs
// 0.128 threshold). Pixels whose T never crosses T_EPS are exact.
__device__ __forceinline__ float eval_alpha(const float4 g0, const float4 g1,
                                            const float px, const float py) {
    const float ddx = px - g0.x;
    const float ddy = py - g0.y;
    const float sg = g0.z*ddx*ddx + g1.x*ddy*ddy + g0.w*ddx*ddy;
    float a = g1.y * expf(-sg);
    return ((sg >= 0.0f) && (a >= ALPHA_MIN)) ? fminf(a, ALPHA_MAX) : 0.0f;
}

__global__ __launch_bounds__(512) void raster_kernel(
    const float4* __restrict__ attrs_s, const float4* __restrict__ bounds_s,
    float* __restrict__ out, int N, int P, const int* __restrict__ wptr)
{
    extern __shared__ int smem[];              // NW * NR ints (per-wave lists)
    __shared__ float s_P[NW][64];              // per-wave, per-pixel segment product
    __shared__ float s_red[NW][64][5];         // per-wave partial accumulators

    const int width  = wptr[0];
    const int height = P / width;
    const int tilesX = (width  + TS - 1) / TS;
    const int tilesY = (height + TS - 1) / TS;
    const int nTiles = tilesX * tilesY;
    const int lane = threadIdx.x & 63;
    const int wv   = threadIdx.x >> 6;

    const int NR = (((N + NW - 1) / NW) + 63) & ~63;   // segment span, mult of 64
    int* s_list = smem + wv * NR;
    const int rstart = wv * NR;
    const int rend   = min(rstart + NR, N);

    for (int tile = blockIdx.x; tile < nTiles; tile += gridDim.x) {
        __syncthreads();   // protect smem reuse across grid-stride iterations

        const int tx = tile % tilesX, ty = tile / tilesX;
        const float x0 = (float)(tx*TS) + 0.5f;
        const float x1 = (float)(min(tx*TS + TS - 1, width  - 1)) + 0.5f;
        const float y0 = (float)(ty*TS) + 0.5f;
        const float y1 = (float)(min(ty*TS + TS - 1, height - 1)) + 0.5f;

        // ---- per-wave cull scan over [rstart, rend): own sub-list, in order
        int count = 0;
        for (int base = rstart; base < rend; base += 64) {
            const int j = base + lane;
            bool pred = false;
            if (j < rend) {
                const float4 b = bounds_s[j];          // mx, my, rad
                pred = (b.z > 0.0f) &&
                       (b.x + b.z >= x0) && (b.x - b.z <= x1) &&
                       (b.y + b.z >= y0) && (b.y - b.z <= y1);
            }
            const unsigned long long m = __ballot(pred);
            const int pre = __popcll(m & ((1ull << lane) - 1ull));
            if (pred) s_list[count + pre] = j;          // sorted position
            count += (int)__popcll(m);
        }
        __syncthreads();

        // ---- pixel for this lane
        const int px_i = tx*TS + (lane & (TS-1));
        const int py_i = ty*TS + (lane >> 3);
        const bool active = (px_i < width) && (py_i < height);
        const float px = (float)px_i + 0.5f;
        const float py = (float)py_i + 0.5f;

        // ---- single pass: local ungated composite + segment product ------
        float Tl = 1.0f;
        float accr = 0.f, accg = 0.f, accb = 0.f, accd = 0.f, acca = 0.f;
        for (int p = 0; p < count; p += 4) {
            const int4 s4 = *reinterpret_cast<const int4*>(&s_list[p]);
            int id[4];
            id[0] = s4.x;
            id[1] = (p+1 < count) ? s4.y : s4.x;
            id[2] = (p+2 < count) ? s4.z : s4.x;
            id[3] = (p+3 < count) ? s4.w : s4.x;
            float al[4];
            float4 G1[4], G2[4];
            #pragma unroll
            for (int u = 0; u < 4; u++) {
                const int idx = __builtin_amdgcn_readfirstlane(id[u]);
                const float4 g0 = attrs_s[idx*3+0];
                G1[u] = attrs_s[idx*3+1];
                G2[u] = attrs_s[idx*3+2];
                const float a = eval_alpha(g0, G1[u], px, py);
                al[u] = (p+u < count) ? a : 0.0f;
            }
            #pragma unroll
            for (int u = 0; u < 4; u++) {
                const float w = al[u] * Tl;
                accr += w * G2[u].x;
                accg += w * G2[u].y;
                accb += w * G2[u].z;
                accd += w * G1[u].z;
                acca += w;
                Tl *= (1.0f - al[u]);
            }
            if (__all(Tl <= T_EPS)) break;   // tail terms telescope to <= T_EPS
        }
        s_P[wv][lane] = Tl;
        __syncthreads();

        // ---- prefix transmittance, scale own accumulators -----------------
        float Ts = active ? 1.0f : 0.0f;
        for (int m = 0; m < wv; m++) Ts *= s_P[m][lane];

        s_red[wv][lane][0] = accr * Ts;
        s_red[wv][lane][1] = accg * Ts;
        s_red[wv][lane][2] = accb * Ts;
        s_red[wv][lane][3] = accd * Ts;
        s_red[wv][lane][4] = acca * Ts;
        __syncthreads();

        if (wv == 0 && active) {
            float r = 0.f, g = 0.f, b = 0.f, d = 0.f, a = 0.f;
            #pragma unroll
            for (int m = 0; m < NW; m++) {
                r += s_red[m][lane][0];
                g += s_red[m][lane][1];
                b += s_red[m][lane][2];
                d += s_red[m][lane][3];
                a += s_red[m][lane][4];
            }
            const int pix = py_i * width + px_i;
            out[pix*4 + 0] = r;
            out[pix*4 + 1] = g;
            out[pix*4 + 2] = b;
            out[pix*4 + 3] = d / fmaxf(a, 1e-10f);
            out[(size_t)P*4 + pix] = a;
        }
    }
}

// ---------------- host-side launch ----------------
extern "C" void kernel_launch(void* const* d_in, const int* in_sizes, int n_in,
                              void* d_out, int out_size, void* d_ws, size_t ws_size,
                              hipStream_t stream) {
    const float* means   = (const float*)d_in[0];
    const float* opac    = (const float*)d_in[1];
    const float* scales  = (const float*)d_in[2];
    const float* quats   = (const float*)d_in[3];
    const float* sh0     = (const float*)d_in[4];
    const float* shN     = (const float*)d_in[5];
    const float* c2w     = (const float*)d_in[6];
    const float* Ks      = (const float*)d_in[7];
    const int*   wptr    = (const int*)d_in[8];
    const int*   hptr    = (const int*)d_in[9];

    const int N = in_sizes[0] / 3;
    const int P = out_size / 5;

    float4* attrs    = (float4*)d_ws;                  // 3*N float4
    float4* attrs_s  = attrs + 3*N;                    // 3*N float4 (sorted)
    float4* bounds_s = attrs_s + 3*N;                  // N float4 (sorted mx,my,rad)
    float*  tz_u     = (float*)(bounds_s + N);         // N floats

    const int gb = (N + 255) / 256;
    hipLaunchKernelGGL(preprocess_kernel, dim3(gb), dim3(256), 0, stream,
                       means, opac, scales, quats, sh0, shN, c2w, Ks, wptr, hptr,
                       attrs, tz_u, N);

    hipLaunchKernelGGL(sort_scatter_kernel, dim3(N), dim3(64), 0, stream,
                       tz_u, attrs, attrs_s, bounds_s, N);

    const int NR = (((N + NW - 1) / NW) + 63) & ~63;
    const size_t lds = (size_t)NW * NR * sizeof(int);
    hipLaunchKernelGGL(raster_kernel, dim3(512), dim3(512), lds, stream,
                       attrs_s, bounds_s, (float*)d_out, N, P, wptr);
}

// Round 10
// 20.633 us; speedup vs baseline: 31.5856x; 1.0459x over previous
//
#include <hip/hip_runtime.h>
#include <math.h>

#define SH_C0f 0.28209479177387814f
#define SH_C1f 0.4886025119029199f
#define EPS2D 0.3f
#define NEAR_PLANE 0.01f
#define FAR_PLANE 1e10f
#define ALPHA_MIN (1.0f/255.0f)
#define ALPHA_MAX 0.999f
#define T_EPS 1e-4f
#define TS 8    // tile size (8x8 pixels)
#define NW 8    // waves per raster block (512 threads)

// ---------------- kernel 1: per-gaussian preprocess (inline 4x4 inverse) ---
__global__ void preprocess_kernel(
    const float* __restrict__ means, const float* __restrict__ opac_in,
    const float* __restrict__ scales, const float* __restrict__ quats,
    const float* __restrict__ sh0, const float* __restrict__ shN,
    const float* __restrict__ c2w, const float* __restrict__ Ks,
    const int* __restrict__ wptr, const int* __restrict__ hptr,
    float4* __restrict__ attrs, float4* __restrict__ bounds, int N)
{
    int i = blockIdx.x * blockDim.x + threadIdx.x;
    if (i >= N) return;

    float m[16];
    #pragma unroll
    for (int k = 0; k < 16; k++) m[k] = c2w[k];
    float inv[12];
    inv[0]  =  m[5]*m[10]*m[15] - m[5]*m[11]*m[14] - m[9]*m[6]*m[15] + m[9]*m[7]*m[14] + m[13]*m[6]*m[11] - m[13]*m[7]*m[10];
    inv[4]  = -m[4]*m[10]*m[15] + m[4]*m[11]*m[14] + m[8]*m[6]*m[15] - m[8]*m[7]*m[14] - m[12]*m[6]*m[11] + m[12]*m[7]*m[10];
    inv[8]  =  m[4]*m[9]*m[15]  - m[4]*m[11]*m[13] - m[8]*m[5]*m[15] + m[8]*m[7]*m[13] + m[12]*m[5]*m[11] - m[12]*m[7]*m[9];
    inv[1]  = -m[1]*m[10]*m[15] + m[1]*m[11]*m[14] + m[9]*m[2]*m[15] - m[9]*m[3]*m[14] - m[13]*m[2]*m[11] + m[13]*m[3]*m[10];
    inv[5]  =  m[0]*m[10]*m[15] - m[0]*m[11]*m[14] - m[8]*m[2]*m[15] + m[8]*m[3]*m[14] + m[12]*m[2]*m[11] - m[12]*m[3]*m[10];
    inv[9]  = -m[0]*m[9]*m[15]  + m[0]*m[11]*m[13] + m[8]*m[1]*m[15] - m[8]*m[3]*m[13] - m[12]*m[1]*m[11] + m[12]*m[3]*m[9];
    inv[2]  =  m[1]*m[6]*m[15]  - m[1]*m[7]*m[14]  - m[5]*m[2]*m[15] + m[5]*m[3]*m[14] + m[13]*m[2]*m[7]  - m[13]*m[3]*m[6];
    inv[6]  = -m[0]*m[6]*m[15]  + m[0]*m[7]*m[14]  + m[4]*m[2]*m[15] - m[4]*m[3]*m[14] - m[12]*m[2]*m[7]  + m[12]*m[3]*m[6];
    inv[10] =  m[0]*m[5]*m[15]  - m[0]*m[7]*m[13]  - m[4]*m[1]*m[15] + m[4]*m[3]*m[13] + m[12]*m[1]*m[7]  - m[12]*m[3]*m[5];
    inv[3]  = -m[1]*m[6]*m[11]  + m[1]*m[7]*m[10]  + m[5]*m[2]*m[11] - m[5]*m[3]*m[10] - m[9]*m[2]*m[7]   + m[9]*m[3]*m[6];
    inv[7]  =  m[0]*m[6]*m[11]  - m[0]*m[7]*m[10]  - m[4]*m[2]*m[11] + m[4]*m[3]*m[10] + m[8]*m[2]*m[7]   - m[8]*m[3]*m[6];
    inv[11] = -m[0]*m[5]*m[11]  + m[0]*m[7]*m[9]   + m[4]*m[1]*m[11] - m[4]*m[3]*m[9]  - m[8]*m[1]*m[7]   + m[8]*m[3]*m[5];
    {
        float inv12 = -m[4]*m[9]*m[14] + m[4]*m[10]*m[13] + m[8]*m[5]*m[14] - m[8]*m[6]*m[13] - m[12]*m[5]*m[10] + m[12]*m[6]*m[9];
        float det = m[0]*inv[0] + m[1]*inv[4] + m[2]*inv[8] + m[3]*inv12;
        float r = 1.0f / det;
        #pragma unroll
        for (int k = 0; k < 12; k++) inv[k] *= r;
    }
    const float W00 = inv[0], W01 = inv[1], W02 = inv[2],  t0 = inv[3];
    const float W10 = inv[4], W11 = inv[5], W12 = inv[6],  t1 = inv[7];
    const float W20 = inv[8], W21 = inv[9], W22 = inv[10], t2 = inv[11];

    const float fx = Ks[0], cx = Ks[2], fy = Ks[4], cy = Ks[5];
    const float width = (float)wptr[0], height = (float)hptr[0];

    const float mxx = means[i*3+0], myy = means[i*3+1], mzz = means[i*3+2];

    const float cpx = m[3], cpy = m[7], cpz = m[11];
    float dx = mxx - cpx, dy = myy - cpy, dz = mzz - cpz;
    float dn = sqrtf(dx*dx + dy*dy + dz*dz);
    dx /= dn; dy /= dn; dz /= dn;

    float col[3];
    #pragma unroll
    for (int c = 0; c < 3; c++) {
        float v = SH_C0f * sh0[i*3+c]
                + SH_C1f * (-dy * shN[i*9 + 0*3 + c] + dz * shN[i*9 + 1*3 + c] - dx * shN[i*9 + 2*3 + c])
                + 0.5f;
        col[c] = fmaxf(v, 0.0f);
    }

    const float op = 1.0f / (1.0f + expf(-opac_in[i]));

    float qw = quats[i*4+0], qx = quats[i*4+1], qy = quats[i*4+2], qz = quats[i*4+3];
    float qn = sqrtf(qw*qw + qx*qx + qy*qy + qz*qz);
    qw /= qn; qx /= qn; qy /= qn; qz /= qn;
    const float R00 = 1.f - 2.f*(qy*qy + qz*qz), R01 = 2.f*(qx*qy - qw*qz), R02 = 2.f*(qx*qz + qw*qy);
    const float R10 = 2.f*(qx*qy + qw*qz), R11 = 1.f - 2.f*(qx*qx + qz*qz), R12 = 2.f*(qy*qz - qw*qx);
    const float R20 = 2.f*(qx*qz - qw*qy), R21 = 2.f*(qy*qz + qw*qx), R22 = 1.f - 2.f*(qx*qx + qy*qy);

    const float sx = scales[i*3+0], sy = scales[i*3+1], sz = scales[i*3+2];
    const float M00 = R00*sx, M01 = R01*sy, M02 = R02*sz;
    const float M10 = R10*sx, M11 = R11*sy, M12 = R12*sz;
    const float M20 = R20*sx, M21 = R21*sy, M22 = R22*sz;

    const float S00 = M00*M00 + M01*M01 + M02*M02;
    const float S01 = M00*M10 + M01*M11 + M02*M12;
    const float S02 = M00*M20 + M01*M21 + M02*M22;
    const float S11 = M10*M10 + M11*M11 + M12*M12;
    const float S12 = M10*M20 + M11*M21 + M12*M22;
    const float S22 = M20*M20 + M21*M21 + M22*M22;

    const float tcx = W00*mxx + W01*myy + W02*mzz + t0;
    const float tcy = W10*mxx + W11*myy + W12*mzz + t1;
    const float tcz = W20*mxx + W21*myy + W22*mzz + t2;
    const float rz = 1.0f / tcz;

    const float limx = 1.3f * (0.5f * width / fx);
    const float limy = 1.3f * (0.5f * height / fy);
    const float txz = fminf(fmaxf(tcx * rz, -limx), limx);
    const float tyz = fminf(fmaxf(tcy * rz, -limy), limy);

    const float V00 = W00*S00 + W01*S01 + W02*S02;
    const float V01 = W00*S01 + W01*S11 + W02*S12;
    const float V02 = W00*S02 + W01*S12 + W02*S22;
    const float V10 = W10*S00 + W11*S01 + W12*S02;
    const float V11 = W10*S01 + W11*S11 + W12*S12;
    const float V12 = W10*S02 + W11*S12 + W12*S22;
    const float V20 = W20*S00 + W21*S01 + W22*S02;
    const float V21 = W20*S01 + W21*S11 + W22*S12;
    const float V22 = W20*S02 + W21*S12 + W22*S22;
    const float CC00 = V00*W00 + V01*W01 + V02*W02;
    const float CC01 = V00*W10 + V01*W11 + V02*W12;
    const float CC02 = V00*W20 + V01*W21 + V02*W22;
    const float CC11 = V10*W10 + V11*W11 + V12*W12;
    const float CC12 = V10*W20 + V11*W21 + V12*W22;
    const float CC22 = V20*W20 + V21*W21 + V22*W22;

    const float j00 = fx * rz,  j02 = -fx * txz * rz;
    const float j11 = fy * rz,  j12 = -fy * tyz * rz;

    const float u0 = j00*CC00 + j02*CC02;
    const float u1 = j00*CC01 + j02*CC12;
    const float u2 = j00*CC02 + j02*CC22;
    const float v1 = j11*CC11 + j12*CC12;
    const float v2 = j11*CC12 + j12*CC22;
    const float c2d00 = u0*j00 + u2*j02;
    const float c2d01 = u1*j11 + u2*j12;
    const float c2d11 = v1*j11 + v2*j12;

    const float a  = c2d00 + EPS2D;
    const float bb = c2d01;
    const float cc = c2d11 + EPS2D;
    const float det = a*cc - bb*bb;
    const float det_safe = (det > 0.0f) ? det : 1.0f;
    const float invd = 1.0f / det_safe;

    const bool valid = (tcz > NEAR_PLANE) && (tcz < FAR_PLANE) && (det > 0.0f);

    float rad = 0.0f;
    if (valid && op >= ALPHA_MIN) {
        const float lmax = 0.5f*(a + cc) + sqrtf(fmaxf(0.f, 0.25f*(a - cc)*(a - cc) + bb*bb));
        const float sig_cut = logf(255.0f * op);
        rad = sqrtf(fmaxf(sig_cut, 0.0f) * 2.0f * lmax) * 1.001f + 0.5f;
    }

    const float mx2d = fx * tcx * rz + cx;
    const float my2d = fy * tcy * rz + cy;

    // HALF conic coefficients (exact power-of-two scale)
    attrs[i*3+0] = make_float4(mx2d, my2d, 0.5f * cc * invd, -bb * invd);  // mx, my, A/2, B
    attrs[i*3+1] = make_float4(0.5f * a * invd, op, tcz, rad);             // C/2, op, tz, rad
    attrs[i*3+2] = make_float4(col[0], col[1], col[2], 0.0f);             // r, g, b
    bounds[i]   = make_float4(mx2d, my2d, rad, 0.0f);
}

// ---- kernel 2: raster. Per tile: ordered cull -> per-tile stable sort -----
// -> single-pass scaled segmented composite (R8 semantics, equal segments).
__device__ __forceinline__ float eval_alpha(const float4 g0, const float4 g1,
                                            const float px, const float py) {
    const float ddx = px - g0.x;
    const float ddy = py - g0.y;
    const float sg = g0.z*ddx*ddx + g1.x*ddy*ddy + g0.w*ddx*ddy;
    float a = g1.y * expf(-sg);
    return ((sg >= 0.0f) && (a >= ALPHA_MIN)) ? fminf(a, ALPHA_MAX) : 0.0f;
}

__global__ __launch_bounds__(512) void raster_kernel(
    const float4* __restrict__ attrs, const float4* __restrict__ bounds,
    float* __restrict__ out, int N, int P, const int* __restrict__ wptr)
{
    extern __shared__ int smem[];     // [N] s_list | [N] s_keys(f32) | [N] s_sorted
    int*   s_list   = smem;
    float* s_keys   = (float*)(smem + N);
    int*   s_sorted = smem + 2*N;
    __shared__ int   s_wcnt[NW];
    __shared__ float s_P[NW][64];
    __shared__ float s_red[NW][64][5];

    const int width  = wptr[0];
    const int height = P / width;
    const int tilesX = (width  + TS - 1) / TS;
    const int tilesY = (height + TS - 1) / TS;
    const int nTiles = tilesX * tilesY;
    const int tid  = threadIdx.x;
    const int lane = tid & 63;
    const int wv   = tid >> 6;

    for (int tile = blockIdx.x; tile < nTiles; tile += gridDim.x) {
        __syncthreads();   // protect smem reuse across grid-stride iterations

        const int tx = tile % tilesX, ty = tile / tilesX;
        const float x0 = (float)(tx*TS) + 0.5f;
        const float x1 = (float)(min(tx*TS + TS - 1, width  - 1)) + 0.5f;
        const float y0 = (float)(ty*TS) + 0.5f;
        const float y1 = (float)(min(ty*TS + TS - 1, height - 1)) + 0.5f;

        // ---- block-wide cull compaction, preserving original index order --
        int count = 0;
        for (int base = 0; base < N; base += 512) {
            const int j = base + tid;
            bool pred = false;
            if (j < N) {
                const float4 b = bounds[j];            // mx, my, rad
                pred = (b.z > 0.0f) &&
                       (b.x + b.z >= x0) && (b.x - b.z <= x1) &&
                       (b.y + b.z >= y0) && (b.y - b.z <= y1);
            }
            const unsigned long long m = __ballot(pred);
            const int pre = __popcll(m & ((1ull << lane) - 1ull));
            if (lane == 0) s_wcnt[wv] = (int)__popcll(m);
            __syncthreads();
            int off = count + pre;
            int tot = 0;
            #pragma unroll
            for (int w = 0; w < NW; w++) {
                if (w < wv) off += s_wcnt[w];
                tot += s_wcnt[w];
            }
            if (pred) s_list[off] = j;
            count += tot;
            __syncthreads();
        }

        // ---- load keys, per-tile stable rank sort by (tz, original idx) ---
        for (int t = tid; t < count; t += 512)
            s_keys[t] = attrs[s_list[t]*3 + 1].z;      // tz
        __syncthreads();
        for (int t = tid; t < count; t += 512) {
            const float kt = s_keys[t];
            int rank = 0;
            for (int mIdx = 0; mIdx < count; mIdx++) {
                const float km = s_keys[mIdx];
                rank += (km < kt) || (km == kt && mIdx < t);  // s_list is idx-ordered
            }
            s_sorted[rank] = s_list[t];
        }
        __syncthreads();

        // ---- pixel for this lane
        const int px_i = tx*TS + (lane & (TS-1));
        const int py_i = ty*TS + (lane >> 3);
        const bool active = (px_i < width) && (py_i < height);
        const float px = (float)px_i + 0.5f;
        const float py = (float)py_i + 0.5f;

        // ---- segmented single-pass scaled composite (equal segments) ------
        const int seg    = (count + NW - 1) / NW;
        const int cstart = wv * seg;
        const int cend   = min(cstart + seg, count);

        float Tl = 1.0f;
        float accr = 0.f, accg = 0.f, accb = 0.f, accd = 0.f, acca = 0.f;
        for (int p = cstart; p < cend; p += 4) {
            int id[4];
            float al[4];
            float4 G1[4], G2[4];
            #pragma unroll
            for (int u = 0; u < 4; u++)
                id[u] = s_sorted[(p+u < cend) ? (p+u) : p];
            #pragma unroll
            for (int u = 0; u < 4; u++) {
                const int idx = __builtin_amdgcn_readfirstlane(id[u]);
                const float4 g0 = attrs[idx*3+0];
                G1[u] = attrs[idx*3+1];
                G2[u] = attrs[idx*3+2];
                const float a = eval_alpha(g0, G1[u], px, py);
                al[u] = (p+u < cend) ? a : 0.0f;
            }
            #pragma unroll
            for (int u = 0; u < 4; u++) {
                const float w = al[u] * Tl;
                accr += w * G2[u].x;
                accg += w * G2[u].y;
                accb += w * G2[u].z;
                accd += w * G1[u].z;
                acca += w;
                Tl *= (1.0f - al[u]);
            }
            if (__all(Tl <= T_EPS)) break;   // tail terms telescope to <= T_EPS
        }
        s_P[wv][lane] = Tl;
        __syncthreads();

        float Ts = active ? 1.0f : 0.0f;
        for (int m = 0; m < wv; m++) Ts *= s_P[m][lane];

        s_red[wv][lane][0] = accr * Ts;
        s_red[wv][lane][1] = accg * Ts;
        s_red[wv][lane][2] = accb * Ts;
        s_red[wv][lane][3] = accd * Ts;
        s_red[wv][lane][4] = acca * Ts;
        __syncthreads();

        if (wv == 0 && active) {
            float r = 0.f, g = 0.f, b = 0.f, d = 0.f, a = 0.f;
            #pragma unroll
            for (int m = 0; m < NW; m++) {
                r += s_red[m][lane][0];
                g += s_red[m][lane][1];
                b += s_red[m][lane][2];
                d += s_red[m][lane][3];
                a += s_red[m][lane][4];
            }
            const int pix = py_i * width + px_i;
            out[pix*4 + 0] = r;
            out[pix*4 + 1] = g;
            out[pix*4 + 2] = b;
            out[pix*4 + 3] = d / fmaxf(a, 1e-10f);
            out[(size_t)P*4 + pix] = a;
        }
    }
}

// ---------------- host-side launch ----------------
extern "C" void kernel_launch(void* const* d_in, const int* in_sizes, int n_in,
                              void* d_out, int out_size, void* d_ws, size_t ws_size,
                              hipStream_t stream) {
    const float* means   = (const float*)d_in[0];
    const float* opac    = (const float*)d_in[1];
    const float* scales  = (const float*)d_in[2];
    const float* quats   = (const float*)d_in[3];
    const float* sh0     = (const float*)d_in[4];
    const float* shN     = (const float*)d_in[5];
    const float* c2w     = (const float*)d_in[6];
    const float* Ks      = (const float*)d_in[7];
    const int*   wptr    = (const int*)d_in[8];
    const int*   hptr    = (const int*)d_in[9];

    const int N = in_sizes[0] / 3;
    const int P = out_size / 5;

    float4* attrs  = (float4*)d_ws;                   // 3*N float4
    float4* bounds = attrs + 3*N;                     // N float4

    const int gb = (N + 255) / 256;
    hipLaunchKernelGGL(preprocess_kernel, dim3(gb), dim3(256), 0, stream,
                       means, opac, scales, quats, sh0, shN, c2w, Ks, wptr, hptr,
                       attrs, bounds, N);

    const size_t lds = (size_t)3 * N * sizeof(int);   // s_list | s_keys | s_sorted
    hipLaunchKernelGGL(raster_kernel, dim3(512), dim3(512), lds, stream,
                       attrs, bounds, (float*)d_out, N, P, wptr);
}